// Round 6
// baseline (532.340 us; speedup 1.0000x reference)
//
#include <hip/hip_runtime.h>
#include <hip/hip_bf16.h>
#include <hip/hip_fp16.h>
#include <cstdint>

// ---------------------------------------------------------------------------
// EpilepsyGNN: 3-layer GAT (4 heads x 32 -> 4x32 -> 1x32), BN(eval)+ReLU
// CSR by dst built once via bucketed two-phase scatter (write-locality fix).
// GEMM = LDS-resident, writes h as f16 + attention logits (f32) in epilogue.
// agg = lane-parallel LDS staging + unrolled channel-parallel f16 gather.
// ---------------------------------------------------------------------------

__device__ __forceinline__ float lrelu02(float x) {
  return x > 0.f ? x : 0.2f * x;
}

// --- edge dtype detection: int64 (little-endian) has all-odd words == 0 -----
__global__ void detect_kernel(const unsigned* __restrict__ ei, int* __restrict__ flag) {
  int lane = threadIdx.x;                 // one wave
  unsigned w = ei[2 * lane + 1];          // odd words 1,3,...,127
  unsigned long long nz = __ballot(w != 0u);
  if (lane == 0) *flag = (nz == 0ull) ? 1 : 0;
}

// --- degree histogram straight from edge_index dst half ---------------------
__global__ void deg_kernel(const void* __restrict__ ei, int E,
                           const int* __restrict__ flag, int* __restrict__ deg) {
  int e = blockIdx.x * blockDim.x + threadIdx.x;
  if (e >= E) return;
  int d;
  if (*flag) d = (int)((const long long*)ei)[(size_t)E + e];
  else       d = ((const int*)ei)[E + e];
  atomicAdd(&deg[d], 1);
}

// --- 3-phase device-wide exclusive scan of (deg[i]+1) -> row_ptr[n+1] -------
// The +1 folds in the self-loop; scanC also places the self-loop at slot 0.
__global__ __launch_bounds__(256) void scanA_kernel(const int* __restrict__ deg,
                                                    int* __restrict__ bsum, int n) {
  int t = threadIdx.x;
  int base = blockIdx.x * 1024 + t * 4;
  int s = 0;
#pragma unroll
  for (int j = 0; j < 4; ++j) {
    int i = base + j;
    if (i < n) s += deg[i] + 1;
  }
#pragma unroll
  for (int off = 32; off >= 1; off >>= 1) s += __shfl_xor(s, off);
  __shared__ int ws[4];
  int lane = t & 63, wid = t >> 6;
  if (lane == 0) ws[wid] = s;
  __syncthreads();
  if (t == 0) bsum[blockIdx.x] = ws[0] + ws[1] + ws[2] + ws[3];
}

__global__ void scanB_kernel(int* __restrict__ bsum, int nb) {
  int lane = threadIdx.x;  // 64 threads
  int carry = 0;
  for (int start = 0; start < nb; start += 64) {
    int i = start + lane;
    int v = (i < nb) ? bsum[i] : 0;
    int inc = v;
#pragma unroll
    for (int off = 1; off < 64; off <<= 1) {
      int u = __shfl_up(inc, off);
      if (lane >= off) inc += u;
    }
    if (i < nb) bsum[i] = inc - v + carry;
    carry += __shfl(inc, 63);
  }
  if (lane == 0) bsum[nb] = carry;
}

__global__ __launch_bounds__(256) void scanC_kernel(const int* __restrict__ deg,
                                                    const int* __restrict__ bsum,
                                                    int* __restrict__ row_ptr,
                                                    int* __restrict__ csr_src,
                                                    int n, int nb) {
  int t = threadIdx.x;
  int lane = t & 63, wid = t >> 6;
  int base = blockIdx.x * 1024 + t * 4;
  int v[4];
  int ts = 0;
#pragma unroll
  for (int j = 0; j < 4; ++j) {
    int i = base + j;
    v[j] = (i < n) ? deg[i] + 1 : 0;
    ts += v[j];
  }
  int inc = ts;
#pragma unroll
  for (int off = 1; off < 64; off <<= 1) {
    int u = __shfl_up(inc, off);
    if (lane >= off) inc += u;
  }
  int wexc = inc - ts;
  __shared__ int wtot[4];
  if (lane == 63) wtot[wid] = inc;
  __syncthreads();
  int wbase = 0;
  for (int w = 0; w < wid; ++w) wbase += wtot[w];
  int run = bsum[blockIdx.x] + wbase + wexc;
#pragma unroll
  for (int j = 0; j < 4; ++j) {
    int i = base + j;
    if (i < n) {
      row_ptr[i] = run;
      csr_src[run] = i;  // self-loop occupies slot 0 of each node's range
      run += v[j];
    }
  }
  if (blockIdx.x == 0 && t == 0) row_ptr[n] = bsum[nb];
}

// --- bucket cursor init: boffs[b] = row_ptr[128b] - 128b --------------------
__global__ void binit_kernel(const int* __restrict__ row_ptr, int* __restrict__ bcursor,
                             int nbk) {
  int b = blockIdx.x * blockDim.x + threadIdx.x;
  if (b < nbk) bcursor[b] = row_ptr[b << 7] - (b << 7);
}

// --- phase 1: bin (src,dst) pairs by dst>>7 ---------------------------------
__global__ void bin_kernel(const void* __restrict__ ei, int E,
                           const int* __restrict__ flag,
                           int* __restrict__ bcursor, int2* __restrict__ binned) {
  int e = blockIdx.x * blockDim.x + threadIdx.x;
  if (e >= E) return;
  int s, d;
  if (*flag) {
    const long long* p = (const long long*)ei;
    s = (int)p[e];
    d = (int)p[(size_t)E + e];
  } else {
    const int* p = (const int*)ei;
    s = p[e];
    d = p[E + e];
  }
  int pos = atomicAdd(&bcursor[d >> 7], 1);
  binned[pos] = make_int2(s, d);
}

// --- phase 2: per-bucket scatter with LDS cursors ---------------------------
__global__ __launch_bounds__(256) void bscatter_kernel(const int2* __restrict__ binned,
                                                       const int* __restrict__ row_ptr,
                                                       int* __restrict__ csr_src, int n) {
  __shared__ int cur[128];
  int b = blockIdx.x;
  int bb = b << 7;
  int nxt = (bb + 128 < n) ? bb + 128 : n;
  int t = threadIdx.x;
  if (t < 128 && bb + t < n) cur[t] = row_ptr[bb + t] + 1;  // +1: skip self-loop slot
  __syncthreads();
  int lo = row_ptr[bb] - bb;
  int hi = row_ptr[nxt] - nxt;
  for (int i = lo + t; i < hi; i += 256) {
    int2 sd = binned[i];
    int pos = atomicAdd(&cur[sd.y - bb], 1);
    csr_src[pos] = sd.x;
  }
}

// --- LDS GEMM + al epilogue: A[n,128]@W[128,OUTC] -> Hout(f16), alS/alD(f32)
template <int BROWS, int BCOLS, int TR, int H>
__global__ __launch_bounds__(256) void gemm_al_kernel(const float* __restrict__ A,
                                                      const float* __restrict__ W,
                                                      const float* __restrict__ a_src,
                                                      const float* __restrict__ a_dst,
                                                      __half* __restrict__ Hout,
                                                      float* __restrict__ alS,
                                                      float* __restrict__ alD,
                                                      int n, int OUTC) {
  constexpr int TC = 4;
  constexpr int CG = BCOLS / TC;   // col groups
  constexpr int RG = BROWS / TR;   // row groups
  static_assert(CG * RG == 256, "256 threads");
  constexpr int AP = 132;          // padded A row stride (floats)

  __shared__ __align__(16) float A_lds[BROWS * AP];
  __shared__ __align__(16) float W_lds[128 * BCOLS];

  const int r0 = blockIdx.x * BROWS;
  const int cb = blockIdx.y * BCOLS;
  const int t = threadIdx.x;

#pragma unroll
  for (int i = 0; i < BROWS / 8; ++i) {
    int slot = t + i * 256;
    int r = slot >> 5;
    int kq = slot & 31;
    float4 v = make_float4(0.f, 0.f, 0.f, 0.f);
    if (r0 + r < n) v = *(const float4*)(A + (size_t)(r0 + r) * 128 + kq * 4);
    *(float4*)&A_lds[r * AP + kq * 4] = v;
  }
#pragma unroll
  for (int i = 0; i < BCOLS / 8; ++i) {
    int slot = t + i * 256;
    int k = slot / (BCOLS / 4);
    int cq = slot % (BCOLS / 4);
    float4 v = *(const float4*)(W + (size_t)k * OUTC + cb + cq * 4);
    *(float4*)&W_lds[k * BCOLS + cq * 4] = v;
  }
  __syncthreads();

  const int cg = t % CG;
  const int rg = t / CG;

  float acc[TR][TC];
#pragma unroll
  for (int i = 0; i < TR; ++i)
#pragma unroll
    for (int j = 0; j < TC; ++j) acc[i][j] = 0.f;

  for (int k4 = 0; k4 < 32; ++k4) {
    float av[TR][4];
#pragma unroll
    for (int i = 0; i < TR; ++i) {
      float4 a4 = *(const float4*)&A_lds[(rg * TR + i) * AP + k4 * 4];
      av[i][0] = a4.x; av[i][1] = a4.y; av[i][2] = a4.z; av[i][3] = a4.w;
    }
#pragma unroll
    for (int kk = 0; kk < 4; ++kk) {
      float4 w4 = *(const float4*)&W_lds[(k4 * 4 + kk) * BCOLS + cg * TC];
#pragma unroll
      for (int i = 0; i < TR; ++i) {
        acc[i][0] = fmaf(av[i][kk], w4.x, acc[i][0]);
        acc[i][1] = fmaf(av[i][kk], w4.y, acc[i][1]);
        acc[i][2] = fmaf(av[i][kk], w4.z, acc[i][2]);
        acc[i][3] = fmaf(av[i][kk], w4.w, acc[i][3]);
      }
    }
  }

  // ---- write f16 h ----
#pragma unroll
  for (int i = 0; i < TR; ++i) {
    int r = r0 + rg * TR + i;
    if (r >= n) continue;
    __half2 lo = __floats2half2_rn(acc[i][0], acc[i][1]);
    __half2 hi = __floats2half2_rn(acc[i][2], acc[i][3]);
    uint2 pk;
    pk.x = *(const unsigned*)&lo;
    pk.y = *(const unsigned*)&hi;
    *(uint2*)(Hout + (size_t)r * OUTC + cb + cg * TC) = pk;
  }

  // ---- al epilogue: reduce over the 8 col-group lanes of each head ----
  const int head = (cb + cg * TC) >> 5;
  const int cLoc = (cg & 7) * 4;
  float as_c[4], ad_c[4];
#pragma unroll
  for (int j = 0; j < 4; ++j) {
    as_c[j] = a_src[head * 32 + cLoc + j];
    ad_c[j] = a_dst[head * 32 + cLoc + j];
  }
#pragma unroll
  for (int i = 0; i < TR; ++i) {
    float ps = acc[i][0] * as_c[0] + acc[i][1] * as_c[1] +
               acc[i][2] * as_c[2] + acc[i][3] * as_c[3];
    float pd = acc[i][0] * ad_c[0] + acc[i][1] * ad_c[1] +
               acc[i][2] * ad_c[2] + acc[i][3] * ad_c[3];
#pragma unroll
    for (int off = 1; off < 8; off <<= 1) {
      ps += __shfl_xor(ps, off);
      pd += __shfl_xor(pd, off);
    }
    if ((cg & 7) == 0) {
      int r = r0 + rg * TR + i;
      if (r < n) {
        alS[(size_t)r * H + head] = ps;
        alD[(size_t)r * H + head] = pd;
      }
    }
  }
}

// --- agg: lane-parallel staging + unrolled channel-parallel f16 gather ------
template <int H, int C, bool BN>
__global__ __launch_bounds__(256) void agg_kernel(
    const int* __restrict__ row_ptr, const int* __restrict__ csr_src,
    const float* __restrict__ alS, const float* __restrict__ alD,
    const __half* __restrict__ hfeat, const float* __restrict__ bias,
    const float* __restrict__ bnw, const float* __restrict__ bnb,
    const float* __restrict__ bnm, const float* __restrict__ bnv,
    float* __restrict__ out, int n) {
  constexpr int HC = H * C;
  constexpr int LPN = (HC >= 128) ? 64 : 32;  // lanes per node
  constexpr int NPB = 256 / LPN;              // node slots per block
  constexpr int KCAP = 96;                    // staged-edge capacity

  __shared__ __align__(16) float sX[NPB][KCAP * H];
  __shared__ int sIdx[NPB][KCAP];

  const int slot = threadIdx.x / LPN;
  const int sl = threadIdx.x % LPN;
  const int v = blockIdx.x * NPB + slot;
  const bool active = v < n;

  int rs = 0, re = 0;
  if (active) { rs = row_ptr[v]; re = row_ptr[v + 1]; }
  const int deg = re - rs;
  const int degS = deg < KCAP ? deg : KCAP;

  float m[H];
#pragma unroll
  for (int h2 = 0; h2 < H; ++h2) m[h2] = -1e30f;

  if constexpr (H == 4) {
    float4 ad4 = make_float4(0.f, 0.f, 0.f, 0.f);
    if (active) ad4 = *(const float4*)(alD + (size_t)v * 4);
    for (int k = sl; k < degS; k += LPN) {
      int s = csr_src[rs + k];
      sIdx[slot][k] = s;
      float4 a4 = *(const float4*)(alS + (size_t)s * 4);
      float x0 = lrelu02(a4.x + ad4.x);
      float x1 = lrelu02(a4.y + ad4.y);
      float x2 = lrelu02(a4.z + ad4.z);
      float x3 = lrelu02(a4.w + ad4.w);
      ((float4*)&sX[slot][0])[k] = make_float4(x0, x1, x2, x3);
      m[0] = fmaxf(m[0], x0); m[1] = fmaxf(m[1], x1);
      m[2] = fmaxf(m[2], x2); m[3] = fmaxf(m[3], x3);
    }
    for (int k = KCAP + sl; k < deg; k += LPN) {
      int s = csr_src[rs + k];
      float4 a4 = *(const float4*)(alS + (size_t)s * 4);
      m[0] = fmaxf(m[0], lrelu02(a4.x + ad4.x));
      m[1] = fmaxf(m[1], lrelu02(a4.y + ad4.y));
      m[2] = fmaxf(m[2], lrelu02(a4.z + ad4.z));
      m[3] = fmaxf(m[3], lrelu02(a4.w + ad4.w));
    }
#pragma unroll
    for (int h2 = 0; h2 < 4; ++h2) {
#pragma unroll
      for (int off = 32; off >= 1; off >>= 1)
        m[h2] = fmaxf(m[h2], __shfl_xor(m[h2], off));
    }
  } else {  // H == 1
    float ad = active ? alD[v] : 0.f;
    for (int k = sl; k < degS; k += LPN) {
      int s = csr_src[rs + k];
      sIdx[slot][k] = s;
      float x = lrelu02(alS[s] + ad);
      sX[slot][k] = x;
      m[0] = fmaxf(m[0], x);
    }
    for (int k = KCAP + sl; k < deg; k += LPN) {
      int s = csr_src[rs + k];
      m[0] = fmaxf(m[0], lrelu02(alS[s] + ad));
    }
#pragma unroll
    for (int off = 16; off >= 1; off >>= 1)
      m[0] = fmaxf(m[0], __shfl_xor(m[0], off));
  }

  __syncthreads();

  if constexpr (H == 4) {
    const int c = 2 * sl;          // channels c, c+1
    const int h = sl >> 4;         // head 0..3
    const float mh = (h == 0) ? m[0] : (h == 1) ? m[1] : (h == 2) ? m[2] : m[3];
    float2 acc = make_float2(0.f, 0.f);
    float den = 0.f;
    int j = 0;
    for (; j + 4 <= degS; j += 4) {
      int s0 = sIdx[slot][j + 0], s1 = sIdx[slot][j + 1];
      int s2 = sIdx[slot][j + 2], s3 = sIdx[slot][j + 3];
      float x0 = sX[slot][(j + 0) * 4 + h];
      float x1 = sX[slot][(j + 1) * 4 + h];
      float x2 = sX[slot][(j + 2) * 4 + h];
      float x3 = sX[slot][(j + 3) * 4 + h];
      __half2 g0 = *(const __half2*)(hfeat + (size_t)s0 * 128 + c);
      __half2 g1 = *(const __half2*)(hfeat + (size_t)s1 * 128 + c);
      __half2 g2 = *(const __half2*)(hfeat + (size_t)s2 * 128 + c);
      __half2 g3 = *(const __half2*)(hfeat + (size_t)s3 * 128 + c);
      float2 f0 = __half22float2(g0);
      float2 f1 = __half22float2(g1);
      float2 f2 = __half22float2(g2);
      float2 f3 = __half22float2(g3);
      float w0 = __expf(x0 - mh), w1 = __expf(x1 - mh);
      float w2 = __expf(x2 - mh), w3 = __expf(x3 - mh);
      den += (w0 + w1) + (w2 + w3);
      acc.x = fmaf(w0, f0.x, acc.x); acc.y = fmaf(w0, f0.y, acc.y);
      acc.x = fmaf(w1, f1.x, acc.x); acc.y = fmaf(w1, f1.y, acc.y);
      acc.x = fmaf(w2, f2.x, acc.x); acc.y = fmaf(w2, f2.y, acc.y);
      acc.x = fmaf(w3, f3.x, acc.x); acc.y = fmaf(w3, f3.y, acc.y);
    }
    for (; j < degS; ++j) {
      int s = sIdx[slot][j];
      float x = sX[slot][j * 4 + h];
      float2 f = __half22float2(*(const __half2*)(hfeat + (size_t)s * 128 + c));
      float w = __expf(x - mh);
      den += w;
      acc.x = fmaf(w, f.x, acc.x); acc.y = fmaf(w, f.y, acc.y);
    }
    if (deg > KCAP) {  // cold fallback, recompute logits
      float adh = alD[(size_t)v * 4 + h];
      for (int e = rs + KCAP; e < re; ++e) {
        int s = csr_src[e];
        float x = lrelu02(alS[(size_t)s * 4 + h] + adh);
        float w = __expf(x - mh);
        den += w;
        float2 f = __half22float2(*(const __half2*)(hfeat + (size_t)s * 128 + c));
        acc.x = fmaf(w, f.x, acc.x); acc.y = fmaf(w, f.y, acc.y);
      }
    }
    if (active) {
      float inv = 1.f / (den + 1e-16f);
      float2 b2v = *(const float2*)(bias + c);
      float g0 = acc.x * inv + b2v.x;
      float g1 = acc.y * inv + b2v.y;
      if constexpr (BN) {
        float2 bw = *(const float2*)(bnw + c);
        float2 bb = *(const float2*)(bnb + c);
        float2 bm = *(const float2*)(bnm + c);
        float2 bv = *(const float2*)(bnv + c);
        g0 = (g0 - bm.x) * (bw.x * rsqrtf(bv.x + 1e-5f)) + bb.x;
        g1 = (g1 - bm.y) * (bw.y * rsqrtf(bv.y + 1e-5f)) + bb.y;
        g0 = fmaxf(g0, 0.f);
        g1 = fmaxf(g1, 0.f);
      }
      *(float2*)(out + (size_t)v * 128 + c) = make_float2(g0, g1);
    }
  } else {  // H == 1, C == 32
    const int c = sl;
    const float mh = m[0];
    float acc = 0.f, den = 0.f;
    int j = 0;
    for (; j + 4 <= degS; j += 4) {
      int s0 = sIdx[slot][j + 0], s1 = sIdx[slot][j + 1];
      int s2 = sIdx[slot][j + 2], s3 = sIdx[slot][j + 3];
      float x0 = sX[slot][j + 0], x1 = sX[slot][j + 1];
      float x2 = sX[slot][j + 2], x3 = sX[slot][j + 3];
      float f0 = __half2float(hfeat[(size_t)s0 * 32 + c]);
      float f1 = __half2float(hfeat[(size_t)s1 * 32 + c]);
      float f2 = __half2float(hfeat[(size_t)s2 * 32 + c]);
      float f3 = __half2float(hfeat[(size_t)s3 * 32 + c]);
      float w0 = __expf(x0 - mh), w1 = __expf(x1 - mh);
      float w2 = __expf(x2 - mh), w3 = __expf(x3 - mh);
      den += (w0 + w1) + (w2 + w3);
      acc = fmaf(w0, f0, acc); acc = fmaf(w1, f1, acc);
      acc = fmaf(w2, f2, acc); acc = fmaf(w3, f3, acc);
    }
    for (; j < degS; ++j) {
      int s = sIdx[slot][j];
      float w = __expf(sX[slot][j] - mh);
      den += w;
      acc = fmaf(w, __half2float(hfeat[(size_t)s * 32 + c]), acc);
    }
    if (deg > KCAP) {
      float ad = alD[v];
      for (int e = rs + KCAP; e < re; ++e) {
        int s = csr_src[e];
        float w = __expf(lrelu02(alS[s] + ad) - mh);
        den += w;
        acc = fmaf(w, __half2float(hfeat[(size_t)s * 32 + c]), acc);
      }
    }
    if (active) {
      out[(size_t)v * 32 + c] = acc / (den + 1e-16f) + bias[c];
    }
  }
}

// ---------------------------------------------------------------------------
extern "C" void kernel_launch(void* const* d_in, const int* in_sizes, int n_in,
                              void* d_out, int out_size, void* d_ws, size_t ws_size,
                              hipStream_t stream) {
  const float* x = (const float*)d_in[0];
  const void* ei = d_in[1];
  const float* w1 = (const float*)d_in[2];
  const float* as1 = (const float*)d_in[3];
  const float* ad1 = (const float*)d_in[4];
  const float* b1 = (const float*)d_in[5];
  const float* bn1w = (const float*)d_in[6];
  const float* bn1b = (const float*)d_in[7];
  const float* bn1m = (const float*)d_in[8];
  const float* bn1v = (const float*)d_in[9];
  const float* w2 = (const float*)d_in[10];
  const float* as2 = (const float*)d_in[11];
  const float* ad2 = (const float*)d_in[12];
  const float* b2 = (const float*)d_in[13];
  const float* bn2w = (const float*)d_in[14];
  const float* bn2b = (const float*)d_in[15];
  const float* bn2m = (const float*)d_in[16];
  const float* bn2v = (const float*)d_in[17];
  const float* w3 = (const float*)d_in[18];
  const float* as3 = (const float*)d_in[19];
  const float* ad3 = (const float*)d_in[20];
  const float* b3 = (const float*)d_in[21];

  const int N = in_sizes[0] / 128;
  const int E = in_sizes[1] / 2;
  const int Etot = E + N;
  const int nb = (N + 1023) / 1024;
  const int nbk = (N + 127) / 128;

  // workspace layout (256B aligned slices)
  char* base = (char*)d_ws;
  size_t off = 0;
  auto alloc = [&](size_t bytes) {
    void* p = base + off;
    off = (off + bytes + 255) & ~(size_t)255;
    return p;
  };
  int* flag = (int*)alloc(4);
  int* deg = (int*)alloc((size_t)N * 4);
  int* row_ptr = (int*)alloc((size_t)(N + 1) * 4);
  int* csr_src = (int*)alloc((size_t)Etot * 4);
  int* bsum = (int*)alloc((size_t)(nb + 1) * 4);
  int* bcursor = (int*)alloc((size_t)nbk * 4);
  int2* binned = (int2*)alloc((size_t)E * 8);
  __half* hbuf = (__half*)alloc((size_t)N * 128 * 2);
  float* gbuf = (float*)alloc((size_t)N * 128 * 4);
  float* alS = (float*)alloc((size_t)N * 4 * 4);
  float* alD = (float*)alloc((size_t)N * 4 * 4);
  (void)ws_size;

  hipMemsetAsync(deg, 0, (size_t)N * 4, stream);

  detect_kernel<<<1, 64, 0, stream>>>((const unsigned*)ei, flag);
  deg_kernel<<<(E + 255) / 256, 256, 0, stream>>>(ei, E, flag, deg);
  scanA_kernel<<<nb, 256, 0, stream>>>(deg, bsum, N);
  scanB_kernel<<<1, 64, 0, stream>>>(bsum, nb);
  scanC_kernel<<<nb, 256, 0, stream>>>(deg, bsum, row_ptr, csr_src, N, nb);
  binit_kernel<<<(nbk + 255) / 256, 256, 0, stream>>>(row_ptr, bcursor, nbk);
  bin_kernel<<<(E + 255) / 256, 256, 0, stream>>>(ei, E, flag, bcursor, binned);
  bscatter_kernel<<<nbk, 256, 0, stream>>>(binned, row_ptr, csr_src, N);

  const int rowBlocks = (N + 63) / 64;

  // ---- layer 1 ----
  gemm_al_kernel<64, 64, 4, 4><<<dim3(rowBlocks, 2), 256, 0, stream>>>(
      x, w1, as1, ad1, hbuf, alS, alD, N, 128);
  agg_kernel<4, 32, true><<<(N + 3) / 4, 256, 0, stream>>>(row_ptr, csr_src, alS, alD, hbuf,
                                                           b1, bn1w, bn1b, bn1m, bn1v, gbuf, N);
  // ---- layer 2 ----
  gemm_al_kernel<64, 64, 4, 4><<<dim3(rowBlocks, 2), 256, 0, stream>>>(
      gbuf, w2, as2, ad2, hbuf, alS, alD, N, 128);
  agg_kernel<4, 32, true><<<(N + 3) / 4, 256, 0, stream>>>(row_ptr, csr_src, alS, alD, hbuf,
                                                           b2, bn2w, bn2b, bn2m, bn2v, gbuf, N);
  // ---- layer 3 ----
  gemm_al_kernel<64, 32, 2, 1><<<dim3(rowBlocks, 1), 256, 0, stream>>>(
      gbuf, w3, as3, ad3, hbuf, alS, alD, N, 32);
  agg_kernel<1, 32, false><<<(N + 7) / 8, 256, 0, stream>>>(row_ptr, csr_src, alS, alD, hbuf,
                                                            b3, nullptr, nullptr, nullptr, nullptr,
                                                            (float*)d_out, N);
}

// Round 7
// 271.770 us; speedup vs baseline: 1.9588x; 1.9588x over previous
//
#include <hip/hip_runtime.h>
#include <hip/hip_bf16.h>
#include <hip/hip_fp16.h>
#include <cstdint>

// ---------------------------------------------------------------------------
// EpilepsyGNN: 3-layer GAT (4 heads x 32 -> 4x32 -> 1x32), BN(eval)+ReLU
// CSR by dst built once via deterministic bucketed two-phase scatter:
//   deg -> scan -> (bcount -> bscan -> bemit) -> bscatter
// No high-contention device atomics (R6 lesson: 800K atomics / 391 addrs =
// 280us of cross-XCD serialization; per-address contention is the metric).
// GEMM = LDS-resident, writes h as f16 + attention logits (f32) in epilogue.
// agg = lane-parallel LDS staging + unrolled channel-parallel f16 gather.
// ---------------------------------------------------------------------------

#define NBCHUNK 128   // edge chunks for bucket counting/emission
#define MAXBK 512     // max buckets (N <= 65536)

__device__ __forceinline__ float lrelu02(float x) {
  return x > 0.f ? x : 0.2f * x;
}

// --- edge dtype detection: int64 (little-endian) has all-odd words == 0 -----
__global__ void detect_kernel(const unsigned* __restrict__ ei, int* __restrict__ flag) {
  int lane = threadIdx.x;                 // one wave
  unsigned w = ei[2 * lane + 1];          // odd words 1,3,...,127
  unsigned long long nz = __ballot(w != 0u);
  if (lane == 0) *flag = (nz == 0ull) ? 1 : 0;
}

// --- degree histogram straight from edge_index dst half ---------------------
__global__ void deg_kernel(const void* __restrict__ ei, int E,
                           const int* __restrict__ flag, int* __restrict__ deg) {
  int e = blockIdx.x * blockDim.x + threadIdx.x;
  if (e >= E) return;
  int d;
  if (*flag) d = (int)((const long long*)ei)[(size_t)E + e];
  else       d = ((const int*)ei)[E + e];
  atomicAdd(&deg[d], 1);   // ~16 ops/address: no contention problem
}

// --- 3-phase device-wide exclusive scan of (deg[i]+1) -> row_ptr[n+1] -------
// The +1 folds in the self-loop; scanC also places the self-loop at slot 0.
__global__ __launch_bounds__(256) void scanA_kernel(const int* __restrict__ deg,
                                                    int* __restrict__ bsum, int n) {
  int t = threadIdx.x;
  int base = blockIdx.x * 1024 + t * 4;
  int s = 0;
#pragma unroll
  for (int j = 0; j < 4; ++j) {
    int i = base + j;
    if (i < n) s += deg[i] + 1;
  }
#pragma unroll
  for (int off = 32; off >= 1; off >>= 1) s += __shfl_xor(s, off);
  __shared__ int ws[4];
  int lane = t & 63, wid = t >> 6;
  if (lane == 0) ws[wid] = s;
  __syncthreads();
  if (t == 0) bsum[blockIdx.x] = ws[0] + ws[1] + ws[2] + ws[3];
}

__global__ void scanB_kernel(int* __restrict__ bsum, int nb) {
  int lane = threadIdx.x;  // 64 threads
  int carry = 0;
  for (int start = 0; start < nb; start += 64) {
    int i = start + lane;
    int v = (i < nb) ? bsum[i] : 0;
    int inc = v;
#pragma unroll
    for (int off = 1; off < 64; off <<= 1) {
      int u = __shfl_up(inc, off);
      if (lane >= off) inc += u;
    }
    if (i < nb) bsum[i] = inc - v + carry;
    carry += __shfl(inc, 63);
  }
  if (lane == 0) bsum[nb] = carry;
}

__global__ __launch_bounds__(256) void scanC_kernel(const int* __restrict__ deg,
                                                    const int* __restrict__ bsum,
                                                    int* __restrict__ row_ptr,
                                                    int* __restrict__ csr_src,
                                                    int n, int nb) {
  int t = threadIdx.x;
  int lane = t & 63, wid = t >> 6;
  int base = blockIdx.x * 1024 + t * 4;
  int v[4];
  int ts = 0;
#pragma unroll
  for (int j = 0; j < 4; ++j) {
    int i = base + j;
    v[j] = (i < n) ? deg[i] + 1 : 0;
    ts += v[j];
  }
  int inc = ts;
#pragma unroll
  for (int off = 1; off < 64; off <<= 1) {
    int u = __shfl_up(inc, off);
    if (lane >= off) inc += u;
  }
  int wexc = inc - ts;
  __shared__ int wtot[4];
  if (lane == 63) wtot[wid] = inc;
  __syncthreads();
  int wbase = 0;
  for (int w = 0; w < wid; ++w) wbase += wtot[w];
  int run = bsum[blockIdx.x] + wbase + wexc;
#pragma unroll
  for (int j = 0; j < 4; ++j) {
    int i = base + j;
    if (i < n) {
      row_ptr[i] = run;
      csr_src[run] = i;  // self-loop occupies slot 0 of each node's range
      run += v[j];
    }
  }
  if (blockIdx.x == 0 && t == 0) row_ptr[n] = bsum[nb];
}

// --- bucket phase 1: per-chunk LDS histogram -> counts[chunk][bucket] -------
__global__ __launch_bounds__(256) void bcount_kernel(const void* __restrict__ ei, int E,
                                                     const int* __restrict__ flag,
                                                     int* __restrict__ counts,
                                                     int nbk, int chunk) {
  __shared__ int hist[MAXBK];
  for (int i = threadIdx.x; i < nbk; i += 256) hist[i] = 0;
  __syncthreads();
  int lo = blockIdx.x * chunk;
  int hi = lo + chunk; if (hi > E) hi = E;
  const bool is64 = (*flag) != 0;
  for (int e = lo + threadIdx.x; e < hi; e += 256) {
    int d = is64 ? (int)((const long long*)ei)[(size_t)E + e] : ((const int*)ei)[E + e];
    atomicAdd(&hist[d >> 7], 1);
  }
  __syncthreads();
  for (int i = threadIdx.x; i < nbk; i += 256)
    counts[(size_t)blockIdx.x * nbk + i] = hist[i];
}

// --- bucket phase 2: per-bucket exclusive scan over chunks -> write bases ---
// grid = nbk blocks, NBCHUNK threads. counts[blk][b] -> base for (blk,b).
__global__ void bscan_kernel(int* __restrict__ counts, const int* __restrict__ row_ptr,
                             int nbk) {
  int b = blockIdx.x;
  int t = threadIdx.x;           // NBCHUNK = 128 threads
  int lane = t & 63, wid = t >> 6;
  int v = counts[(size_t)t * nbk + b];
  int inc = v;
#pragma unroll
  for (int off = 1; off < 64; off <<= 1) {
    int u = __shfl_up(inc, off);
    if (lane >= off) inc += u;
  }
  __shared__ int wt[2];
  if (lane == 63) wt[wid] = inc;
  __syncthreads();
  int wbase = (wid == 1) ? wt[0] : 0;
  int bb = b << 7;
  int bucket_base = row_ptr[bb] - bb;   // edges-before-bucket (self-loops removed)
  counts[(size_t)t * nbk + b] = bucket_base + wbase + (inc - v);
}

// --- bucket phase 3: emit (src,dst) into bucket-contiguous binned ----------
__global__ __launch_bounds__(256) void bemit_kernel(const void* __restrict__ ei, int E,
                                                    const int* __restrict__ flag,
                                                    const int* __restrict__ counts,
                                                    int nbk, int chunk,
                                                    int2* __restrict__ binned) {
  __shared__ int cur[MAXBK];
  for (int i = threadIdx.x; i < nbk; i += 256)
    cur[i] = counts[(size_t)blockIdx.x * nbk + i];
  __syncthreads();
  int lo = blockIdx.x * chunk;
  int hi = lo + chunk; if (hi > E) hi = E;
  const bool is64 = (*flag) != 0;
  for (int e = lo + threadIdx.x; e < hi; e += 256) {
    int s, d;
    if (is64) {
      const long long* p = (const long long*)ei;
      s = (int)p[e];
      d = (int)p[(size_t)E + e];
    } else {
      const int* p = (const int*)ei;
      s = p[e];
      d = p[E + e];
    }
    int pos = atomicAdd(&cur[d >> 7], 1);   // LDS atomic: cheap
    binned[pos] = make_int2(s, d);
  }
}

// --- phase 4: per-bucket scatter with LDS cursors ---------------------------
__global__ __launch_bounds__(256) void bscatter_kernel(const int2* __restrict__ binned,
                                                       const int* __restrict__ row_ptr,
                                                       int* __restrict__ csr_src, int n) {
  __shared__ int cur[128];
  int b = blockIdx.x;
  int bb = b << 7;
  int nxt = (bb + 128 < n) ? bb + 128 : n;
  int t = threadIdx.x;
  if (t < 128 && bb + t < n) cur[t] = row_ptr[bb + t] + 1;  // +1: skip self-loop slot
  __syncthreads();
  int lo = row_ptr[bb] - bb;
  int hi = row_ptr[nxt] - nxt;
  for (int i = lo + t; i < hi; i += 256) {
    int2 sd = binned[i];
    int pos = atomicAdd(&cur[sd.y - bb], 1);
    csr_src[pos] = sd.x;
  }
}

// --- LDS GEMM + al epilogue: A[n,128]@W[128,OUTC] -> Hout(f16), alS/alD(f32)
template <int BROWS, int BCOLS, int TR, int H>
__global__ __launch_bounds__(256) void gemm_al_kernel(const float* __restrict__ A,
                                                      const float* __restrict__ W,
                                                      const float* __restrict__ a_src,
                                                      const float* __restrict__ a_dst,
                                                      __half* __restrict__ Hout,
                                                      float* __restrict__ alS,
                                                      float* __restrict__ alD,
                                                      int n, int OUTC) {
  constexpr int TC = 4;
  constexpr int CG = BCOLS / TC;   // col groups
  constexpr int RG = BROWS / TR;   // row groups
  static_assert(CG * RG == 256, "256 threads");
  constexpr int AP = 132;          // padded A row stride (floats)

  __shared__ __align__(16) float A_lds[BROWS * AP];
  __shared__ __align__(16) float W_lds[128 * BCOLS];

  const int r0 = blockIdx.x * BROWS;
  const int cb = blockIdx.y * BCOLS;
  const int t = threadIdx.x;

#pragma unroll
  for (int i = 0; i < BROWS / 8; ++i) {
    int slot = t + i * 256;
    int r = slot >> 5;
    int kq = slot & 31;
    float4 v = make_float4(0.f, 0.f, 0.f, 0.f);
    if (r0 + r < n) v = *(const float4*)(A + (size_t)(r0 + r) * 128 + kq * 4);
    *(float4*)&A_lds[r * AP + kq * 4] = v;
  }
#pragma unroll
  for (int i = 0; i < BCOLS / 8; ++i) {
    int slot = t + i * 256;
    int k = slot / (BCOLS / 4);
    int cq = slot % (BCOLS / 4);
    float4 v = *(const float4*)(W + (size_t)k * OUTC + cb + cq * 4);
    *(float4*)&W_lds[k * BCOLS + cq * 4] = v;
  }
  __syncthreads();

  const int cg = t % CG;
  const int rg = t / CG;

  float acc[TR][TC];
#pragma unroll
  for (int i = 0; i < TR; ++i)
#pragma unroll
    for (int j = 0; j < TC; ++j) acc[i][j] = 0.f;

  for (int k4 = 0; k4 < 32; ++k4) {
    float av[TR][4];
#pragma unroll
    for (int i = 0; i < TR; ++i) {
      float4 a4 = *(const float4*)&A_lds[(rg * TR + i) * AP + k4 * 4];
      av[i][0] = a4.x; av[i][1] = a4.y; av[i][2] = a4.z; av[i][3] = a4.w;
    }
#pragma unroll
    for (int kk = 0; kk < 4; ++kk) {
      float4 w4 = *(const float4*)&W_lds[(k4 * 4 + kk) * BCOLS + cg * TC];
#pragma unroll
      for (int i = 0; i < TR; ++i) {
        acc[i][0] = fmaf(av[i][kk], w4.x, acc[i][0]);
        acc[i][1] = fmaf(av[i][kk], w4.y, acc[i][1]);
        acc[i][2] = fmaf(av[i][kk], w4.z, acc[i][2]);
        acc[i][3] = fmaf(av[i][kk], w4.w, acc[i][3]);
      }
    }
  }

  // ---- write f16 h ----
#pragma unroll
  for (int i = 0; i < TR; ++i) {
    int r = r0 + rg * TR + i;
    if (r >= n) continue;
    __half2 lo = __floats2half2_rn(acc[i][0], acc[i][1]);
    __half2 hi = __floats2half2_rn(acc[i][2], acc[i][3]);
    uint2 pk;
    pk.x = *(const unsigned*)&lo;
    pk.y = *(const unsigned*)&hi;
    *(uint2*)(Hout + (size_t)r * OUTC + cb + cg * TC) = pk;
  }

  // ---- al epilogue: reduce over the 8 col-group lanes of each head ----
  const int head = (cb + cg * TC) >> 5;
  const int cLoc = (cg & 7) * 4;
  float as_c[4], ad_c[4];
#pragma unroll
  for (int j = 0; j < 4; ++j) {
    as_c[j] = a_src[head * 32 + cLoc + j];
    ad_c[j] = a_dst[head * 32 + cLoc + j];
  }
#pragma unroll
  for (int i = 0; i < TR; ++i) {
    float ps = acc[i][0] * as_c[0] + acc[i][1] * as_c[1] +
               acc[i][2] * as_c[2] + acc[i][3] * as_c[3];
    float pd = acc[i][0] * ad_c[0] + acc[i][1] * ad_c[1] +
               acc[i][2] * ad_c[2] + acc[i][3] * ad_c[3];
#pragma unroll
    for (int off = 1; off < 8; off <<= 1) {
      ps += __shfl_xor(ps, off);
      pd += __shfl_xor(pd, off);
    }
    if ((cg & 7) == 0) {
      int r = r0 + rg * TR + i;
      if (r < n) {
        alS[(size_t)r * H + head] = ps;
        alD[(size_t)r * H + head] = pd;
      }
    }
  }
}

// --- agg: lane-parallel staging + unrolled channel-parallel f16 gather ------
template <int H, int C, bool BN>
__global__ __launch_bounds__(256) void agg_kernel(
    const int* __restrict__ row_ptr, const int* __restrict__ csr_src,
    const float* __restrict__ alS, const float* __restrict__ alD,
    const __half* __restrict__ hfeat, const float* __restrict__ bias,
    const float* __restrict__ bnw, const float* __restrict__ bnb,
    const float* __restrict__ bnm, const float* __restrict__ bnv,
    float* __restrict__ out, int n) {
  constexpr int HC = H * C;
  constexpr int LPN = (HC >= 128) ? 64 : 32;  // lanes per node
  constexpr int NPB = 256 / LPN;              // node slots per block
  constexpr int KCAP = 96;                    // staged-edge capacity

  __shared__ __align__(16) float sX[NPB][KCAP * H];
  __shared__ int sIdx[NPB][KCAP];

  const int slot = threadIdx.x / LPN;
  const int sl = threadIdx.x % LPN;
  const int v = blockIdx.x * NPB + slot;
  const bool active = v < n;

  int rs = 0, re = 0;
  if (active) { rs = row_ptr[v]; re = row_ptr[v + 1]; }
  const int deg = re - rs;
  const int degS = deg < KCAP ? deg : KCAP;

  float m[H];
#pragma unroll
  for (int h2 = 0; h2 < H; ++h2) m[h2] = -1e30f;

  if constexpr (H == 4) {
    float4 ad4 = make_float4(0.f, 0.f, 0.f, 0.f);
    if (active) ad4 = *(const float4*)(alD + (size_t)v * 4);
    for (int k = sl; k < degS; k += LPN) {
      int s = csr_src[rs + k];
      sIdx[slot][k] = s;
      float4 a4 = *(const float4*)(alS + (size_t)s * 4);
      float x0 = lrelu02(a4.x + ad4.x);
      float x1 = lrelu02(a4.y + ad4.y);
      float x2 = lrelu02(a4.z + ad4.z);
      float x3 = lrelu02(a4.w + ad4.w);
      ((float4*)&sX[slot][0])[k] = make_float4(x0, x1, x2, x3);
      m[0] = fmaxf(m[0], x0); m[1] = fmaxf(m[1], x1);
      m[2] = fmaxf(m[2], x2); m[3] = fmaxf(m[3], x3);
    }
    for (int k = KCAP + sl; k < deg; k += LPN) {
      int s = csr_src[rs + k];
      float4 a4 = *(const float4*)(alS + (size_t)s * 4);
      m[0] = fmaxf(m[0], lrelu02(a4.x + ad4.x));
      m[1] = fmaxf(m[1], lrelu02(a4.y + ad4.y));
      m[2] = fmaxf(m[2], lrelu02(a4.z + ad4.z));
      m[3] = fmaxf(m[3], lrelu02(a4.w + ad4.w));
    }
#pragma unroll
    for (int h2 = 0; h2 < 4; ++h2) {
#pragma unroll
      for (int off = 32; off >= 1; off >>= 1)
        m[h2] = fmaxf(m[h2], __shfl_xor(m[h2], off));
    }
  } else {  // H == 1
    float ad = active ? alD[v] : 0.f;
    for (int k = sl; k < degS; k += LPN) {
      int s = csr_src[rs + k];
      sIdx[slot][k] = s;
      float x = lrelu02(alS[s] + ad);
      sX[slot][k] = x;
      m[0] = fmaxf(m[0], x);
    }
    for (int k = KCAP + sl; k < deg; k += LPN) {
      int s = csr_src[rs + k];
      m[0] = fmaxf(m[0], lrelu02(alS[s] + ad));
    }
#pragma unroll
    for (int off = 16; off >= 1; off >>= 1)
      m[0] = fmaxf(m[0], __shfl_xor(m[0], off));
  }

  __syncthreads();

  if constexpr (H == 4) {
    const int c = 2 * sl;          // channels c, c+1
    const int h = sl >> 4;         // head 0..3
    const float mh = (h == 0) ? m[0] : (h == 1) ? m[1] : (h == 2) ? m[2] : m[3];
    float2 acc = make_float2(0.f, 0.f);
    float den = 0.f;
    int j = 0;
    for (; j + 4 <= degS; j += 4) {
      int s0 = sIdx[slot][j + 0], s1 = sIdx[slot][j + 1];
      int s2 = sIdx[slot][j + 2], s3 = sIdx[slot][j + 3];
      float x0 = sX[slot][(j + 0) * 4 + h];
      float x1 = sX[slot][(j + 1) * 4 + h];
      float x2 = sX[slot][(j + 2) * 4 + h];
      float x3 = sX[slot][(j + 3) * 4 + h];
      __half2 g0 = *(const __half2*)(hfeat + (size_t)s0 * 128 + c);
      __half2 g1 = *(const __half2*)(hfeat + (size_t)s1 * 128 + c);
      __half2 g2 = *(const __half2*)(hfeat + (size_t)s2 * 128 + c);
      __half2 g3 = *(const __half2*)(hfeat + (size_t)s3 * 128 + c);
      float2 f0 = __half22float2(g0);
      float2 f1 = __half22float2(g1);
      float2 f2 = __half22float2(g2);
      float2 f3 = __half22float2(g3);
      float w0 = __expf(x0 - mh), w1 = __expf(x1 - mh);
      float w2 = __expf(x2 - mh), w3 = __expf(x3 - mh);
      den += (w0 + w1) + (w2 + w3);
      acc.x = fmaf(w0, f0.x, acc.x); acc.y = fmaf(w0, f0.y, acc.y);
      acc.x = fmaf(w1, f1.x, acc.x); acc.y = fmaf(w1, f1.y, acc.y);
      acc.x = fmaf(w2, f2.x, acc.x); acc.y = fmaf(w2, f2.y, acc.y);
      acc.x = fmaf(w3, f3.x, acc.x); acc.y = fmaf(w3, f3.y, acc.y);
    }
    for (; j < degS; ++j) {
      int s = sIdx[slot][j];
      float x = sX[slot][j * 4 + h];
      float2 f = __half22float2(*(const __half2*)(hfeat + (size_t)s * 128 + c));
      float w = __expf(x - mh);
      den += w;
      acc.x = fmaf(w, f.x, acc.x); acc.y = fmaf(w, f.y, acc.y);
    }
    if (deg > KCAP) {  // cold fallback, recompute logits
      float adh = alD[(size_t)v * 4 + h];
      for (int e = rs + KCAP; e < re; ++e) {
        int s = csr_src[e];
        float x = lrelu02(alS[(size_t)s * 4 + h] + adh);
        float w = __expf(x - mh);
        den += w;
        float2 f = __half22float2(*(const __half2*)(hfeat + (size_t)s * 128 + c));
        acc.x = fmaf(w, f.x, acc.x); acc.y = fmaf(w, f.y, acc.y);
      }
    }
    if (active) {
      float inv = 1.f / (den + 1e-16f);
      float2 b2v = *(const float2*)(bias + c);
      float g0 = acc.x * inv + b2v.x;
      float g1 = acc.y * inv + b2v.y;
      if constexpr (BN) {
        float2 bw = *(const float2*)(bnw + c);
        float2 bb = *(const float2*)(bnb + c);
        float2 bm = *(const float2*)(bnm + c);
        float2 bv = *(const float2*)(bnv + c);
        g0 = (g0 - bm.x) * (bw.x * rsqrtf(bv.x + 1e-5f)) + bb.x;
        g1 = (g1 - bm.y) * (bw.y * rsqrtf(bv.y + 1e-5f)) + bb.y;
        g0 = fmaxf(g0, 0.f);
        g1 = fmaxf(g1, 0.f);
      }
      *(float2*)(out + (size_t)v * 128 + c) = make_float2(g0, g1);
    }
  } else {  // H == 1, C == 32
    const int c = sl;
    const float mh = m[0];
    float acc = 0.f, den = 0.f;
    int j = 0;
    for (; j + 4 <= degS; j += 4) {
      int s0 = sIdx[slot][j + 0], s1 = sIdx[slot][j + 1];
      int s2 = sIdx[slot][j + 2], s3 = sIdx[slot][j + 3];
      float x0 = sX[slot][j + 0], x1 = sX[slot][j + 1];
      float x2 = sX[slot][j + 2], x3 = sX[slot][j + 3];
      float f0 = __half2float(hfeat[(size_t)s0 * 32 + c]);
      float f1 = __half2float(hfeat[(size_t)s1 * 32 + c]);
      float f2 = __half2float(hfeat[(size_t)s2 * 32 + c]);
      float f3 = __half2float(hfeat[(size_t)s3 * 32 + c]);
      float w0 = __expf(x0 - mh), w1 = __expf(x1 - mh);
      float w2 = __expf(x2 - mh), w3 = __expf(x3 - mh);
      den += (w0 + w1) + (w2 + w3);
      acc = fmaf(w0, f0, acc); acc = fmaf(w1, f1, acc);
      acc = fmaf(w2, f2, acc); acc = fmaf(w3, f3, acc);
    }
    for (; j < degS; ++j) {
      int s = sIdx[slot][j];
      float w = __expf(sX[slot][j] - mh);
      den += w;
      acc = fmaf(w, __half2float(hfeat[(size_t)s * 32 + c]), acc);
    }
    if (deg > KCAP) {
      float ad = alD[v];
      for (int e = rs + KCAP; e < re; ++e) {
        int s = csr_src[e];
        float w = __expf(lrelu02(alS[s] + ad) - mh);
        den += w;
        acc = fmaf(w, __half2float(hfeat[(size_t)s * 32 + c]), acc);
      }
    }
    if (active) {
      out[(size_t)v * 32 + c] = acc / (den + 1e-16f) + bias[c];
    }
  }
}

// ---------------------------------------------------------------------------
extern "C" void kernel_launch(void* const* d_in, const int* in_sizes, int n_in,
                              void* d_out, int out_size, void* d_ws, size_t ws_size,
                              hipStream_t stream) {
  const float* x = (const float*)d_in[0];
  const void* ei = d_in[1];
  const float* w1 = (const float*)d_in[2];
  const float* as1 = (const float*)d_in[3];
  const float* ad1 = (const float*)d_in[4];
  const float* b1 = (const float*)d_in[5];
  const float* bn1w = (const float*)d_in[6];
  const float* bn1b = (const float*)d_in[7];
  const float* bn1m = (const float*)d_in[8];
  const float* bn1v = (const float*)d_in[9];
  const float* w2 = (const float*)d_in[10];
  const float* as2 = (const float*)d_in[11];
  const float* ad2 = (const float*)d_in[12];
  const float* b2 = (const float*)d_in[13];
  const float* bn2w = (const float*)d_in[14];
  const float* bn2b = (const float*)d_in[15];
  const float* bn2m = (const float*)d_in[16];
  const float* bn2v = (const float*)d_in[17];
  const float* w3 = (const float*)d_in[18];
  const float* as3 = (const float*)d_in[19];
  const float* ad3 = (const float*)d_in[20];
  const float* b3 = (const float*)d_in[21];

  const int N = in_sizes[0] / 128;
  const int E = in_sizes[1] / 2;
  const int Etot = E + N;
  const int nb = (N + 1023) / 1024;
  const int nbk = (N + 127) / 128;
  const int chunk = (E + NBCHUNK - 1) / NBCHUNK;

  // workspace layout (256B aligned slices)
  char* base = (char*)d_ws;
  size_t off = 0;
  auto alloc = [&](size_t bytes) {
    void* p = base + off;
    off = (off + bytes + 255) & ~(size_t)255;
    return p;
  };
  int* flag = (int*)alloc(4);
  int* deg = (int*)alloc((size_t)N * 4);
  int* row_ptr = (int*)alloc((size_t)(N + 1) * 4);
  int* csr_src = (int*)alloc((size_t)Etot * 4);
  int* bsum = (int*)alloc((size_t)(nb + 1) * 4);
  int* counts = (int*)alloc((size_t)NBCHUNK * nbk * 4);
  int2* binned = (int2*)alloc((size_t)E * 8);
  __half* hbuf = (__half*)alloc((size_t)N * 128 * 2);
  float* gbuf = (float*)alloc((size_t)N * 128 * 4);
  float* alS = (float*)alloc((size_t)N * 4 * 4);
  float* alD = (float*)alloc((size_t)N * 4 * 4);
  (void)ws_size;

  hipMemsetAsync(deg, 0, (size_t)N * 4, stream);

  detect_kernel<<<1, 64, 0, stream>>>((const unsigned*)ei, flag);
  deg_kernel<<<(E + 255) / 256, 256, 0, stream>>>(ei, E, flag, deg);
  scanA_kernel<<<nb, 256, 0, stream>>>(deg, bsum, N);
  scanB_kernel<<<1, 64, 0, stream>>>(bsum, nb);
  scanC_kernel<<<nb, 256, 0, stream>>>(deg, bsum, row_ptr, csr_src, N, nb);
  bcount_kernel<<<NBCHUNK, 256, 0, stream>>>(ei, E, flag, counts, nbk, chunk);
  bscan_kernel<<<nbk, NBCHUNK, 0, stream>>>(counts, row_ptr, nbk);
  bemit_kernel<<<NBCHUNK, 256, 0, stream>>>(ei, E, flag, counts, nbk, chunk, binned);
  bscatter_kernel<<<nbk, 256, 0, stream>>>(binned, row_ptr, csr_src, N);

  const int rowBlocks = (N + 63) / 64;

  // ---- layer 1 ----
  gemm_al_kernel<64, 64, 4, 4><<<dim3(rowBlocks, 2), 256, 0, stream>>>(
      x, w1, as1, ad1, hbuf, alS, alD, N, 128);
  agg_kernel<4, 32, true><<<(N + 3) / 4, 256, 0, stream>>>(row_ptr, csr_src, alS, alD, hbuf,
                                                           b1, bn1w, bn1b, bn1m, bn1v, gbuf, N);
  // ---- layer 2 ----
  gemm_al_kernel<64, 64, 4, 4><<<dim3(rowBlocks, 2), 256, 0, stream>>>(
      gbuf, w2, as2, ad2, hbuf, alS, alD, N, 128);
  agg_kernel<4, 32, true><<<(N + 3) / 4, 256, 0, stream>>>(row_ptr, csr_src, alS, alD, hbuf,
                                                           b2, bn2w, bn2b, bn2m, bn2v, gbuf, N);
  // ---- layer 3 ----
  gemm_al_kernel<64, 32, 2, 1><<<dim3(rowBlocks, 1), 256, 0, stream>>>(
      gbuf, w3, as3, ad3, hbuf, alS, alD, N, 32);
  agg_kernel<1, 32, false><<<(N + 7) / 8, 256, 0, stream>>>(row_ptr, csr_src, alS, alD, hbuf,
                                                            b3, nullptr, nullptr, nullptr, nullptr,
                                                            (float*)d_out, N);
}

// Round 9
// 222.630 us; speedup vs baseline: 2.3911x; 1.2207x over previous
//
#include <hip/hip_runtime.h>
#include <hip/hip_fp16.h>
#include <cstdint>

// ---------------------------------------------------------------------------
// EpilepsyGNN: 3-layer GAT (4 heads x 32 -> 4x32 -> 1x32), BN(eval)+ReLU
// CSR build: bucket counts -> chunk scan -> bucket scan -> packed emit ->
// per-bucket scatter deriving row_ptr from its own LDS histogram. Zero global
// atomics. agg: softmax WITHOUT max-subtraction (scale-invariant; logits
// bounded, insurance clamp at 80), exp hoisted to staging, inner loop = pure
// f16 gather+fmaf. Layer activations f16 end-to-end; all math f32.
// R8 bug fixed: f16 A-staging read 16B chunks via uint2 (8B) -> stack garbage.
// ---------------------------------------------------------------------------

#define NBCHUNK 128   // edge chunks for bucket counting/emission
#define MAXBK 512     // max buckets of 128 nodes (N <= 65536; packing needs it)

__device__ __forceinline__ float lrelu02(float x) {
  return x > 0.f ? x : 0.2f * x;
}

__device__ __forceinline__ float expw(float x) {
  return __expf(fminf(x, 80.f));   // clamp is a no-op for this data; inf guard
}

// --- edge dtype detection: int64 (little-endian) has all-odd words == 0 -----
__global__ void detect_kernel(const unsigned* __restrict__ ei, int* __restrict__ flag) {
  int lane = threadIdx.x;                 // one wave
  unsigned w = ei[2 * lane + 1];          // odd words 1,3,...,127
  unsigned long long nz = __ballot(w != 0u);
  if (lane == 0) *flag = (nz == 0ull) ? 1 : 0;
}

// --- phase 1: per-chunk LDS histogram of dst buckets ------------------------
__global__ __launch_bounds__(256) void bcount_kernel(const void* __restrict__ ei, int E,
                                                     const int* __restrict__ flag,
                                                     int* __restrict__ counts,
                                                     int nbk, int chunk) {
  __shared__ int hist[MAXBK];
  for (int i = threadIdx.x; i < nbk; i += 256) hist[i] = 0;
  __syncthreads();
  int lo = blockIdx.x * chunk;
  int hi = lo + chunk; if (hi > E) hi = E;
  const bool is64 = (*flag) != 0;
  for (int e = lo + threadIdx.x; e < hi; e += 256) {
    int d = is64 ? (int)((const long long*)ei)[(size_t)E + e] : ((const int*)ei)[E + e];
    atomicAdd(&hist[d >> 7], 1);
  }
  __syncthreads();
  for (int i = threadIdx.x; i < nbk; i += 256)
    counts[(size_t)blockIdx.x * nbk + i] = hist[i];
}

// --- phase 2a: per-bucket exclusive scan over chunks; totals -> T -----------
__global__ void bscanT_kernel(int* __restrict__ counts, int* __restrict__ T, int nbk) {
  int b = blockIdx.x;
  int t = threadIdx.x;           // NBCHUNK = 128 threads
  int lane = t & 63;
  int v = counts[(size_t)t * nbk + b];
  int inc = v;
#pragma unroll
  for (int off = 1; off < 64; off <<= 1) {
    int u = __shfl_up(inc, off);
    if (lane >= off) inc += u;
  }
  __shared__ int w0;
  if (t == 63) w0 = inc;
  __syncthreads();
  int wb = (t >= 64) ? w0 : 0;
  counts[(size_t)t * nbk + b] = wb + inc - v;   // chunk-exclusive, bucket-local
  if (t == 127) T[b] = wb + inc;                // bucket edge total
}

// --- phase 2b: single-wave exclusive scan of bucket totals -> EB ------------
__global__ void bscanE_kernel(const int* __restrict__ T, int* __restrict__ EB, int nbk) {
  int lane = threadIdx.x;  // 64 threads
  int carry = 0;
  for (int start = 0; start < nbk; start += 64) {
    int i = start + lane;
    int v = (i < nbk) ? T[i] : 0;
    int inc = v;
#pragma unroll
    for (int off = 1; off < 64; off <<= 1) {
      int u = __shfl_up(inc, off);
      if (lane >= off) inc += u;
    }
    if (i < nbk) EB[i] = inc - v + carry;
    carry += __shfl(inc, 63);
  }
  if (lane == 0) EB[nbk] = carry;
}

// --- phase 3: emit packed (dloc<<16 | src) bucket-contiguously --------------
__global__ __launch_bounds__(256) void bemit_kernel(const void* __restrict__ ei, int E,
                                                    const int* __restrict__ flag,
                                                    const int* __restrict__ counts,
                                                    const int* __restrict__ EB,
                                                    int nbk, int chunk,
                                                    unsigned* __restrict__ binned) {
  __shared__ int cur[MAXBK];
  for (int i = threadIdx.x; i < nbk; i += 256)
    cur[i] = counts[(size_t)blockIdx.x * nbk + i] + EB[i];
  __syncthreads();
  int lo = blockIdx.x * chunk;
  int hi = lo + chunk; if (hi > E) hi = E;
  const bool is64 = (*flag) != 0;
  for (int e = lo + threadIdx.x; e < hi; e += 256) {
    int s, d;
    if (is64) {
      const long long* p = (const long long*)ei;
      s = (int)p[e];
      d = (int)p[(size_t)E + e];
    } else {
      const int* p = (const int*)ei;
      s = p[e];
      d = p[E + e];
    }
    int pos = atomicAdd(&cur[d >> 7], 1);   // LDS atomic: cheap
    binned[pos] = ((unsigned)(d & 127) << 16) | (unsigned)s;   // N <= 65536
  }
}

// --- phase 4: per-bucket histogram -> row_ptr + self-loops + scatter --------
__global__ __launch_bounds__(256) void bscatter2_kernel(const unsigned* __restrict__ binned,
                                                        const int* __restrict__ EB,
                                                        int* __restrict__ row_ptr,
                                                        int* __restrict__ csr_src,
                                                        int n, int E) {
  __shared__ int hist[128];
  __shared__ int cur[128];
  __shared__ int w0s;
  const int b = blockIdx.x;
  const int t = threadIdx.x;
  const int bb = b << 7;
  if (t < 128) hist[t] = 0;
  __syncthreads();
  const int lo = EB[b], hi = EB[b + 1];
  for (int i = lo + t; i < hi; i += 256)
    atomicAdd(&hist[binned[i] >> 16], 1);
  __syncthreads();
  // exclusive scan of hist[0..127] (waves 0,1 carry real data)
  int lane = t & 63;
  int v = (t < 128) ? hist[t] : 0;
  int inc = v;
#pragma unroll
  for (int off = 1; off < 64; off <<= 1) {
    int u = __shfl_up(inc, off);
    if (lane >= off) inc += u;
  }
  if (t == 63) w0s = inc;
  __syncthreads();
  int exc = ((t >= 64 && t < 128) ? w0s : 0) + inc - v;
  if (t < 128 && bb + t < n) {
    int rp = EB[b] + bb + t + exc;   // edges-before-node + self-loops-before
    row_ptr[bb + t] = rp;
    csr_src[rp] = bb + t;            // self loop at slot 0
    cur[t] = rp + 1;
  }
  if (b == 0 && t == 0) row_ptr[n] = E + n;
  __syncthreads();
  for (int i = lo + t; i < hi; i += 256) {
    unsigned pv = binned[i];
    int pos = atomicAdd(&cur[pv >> 16], 1);
    csr_src[pos] = (int)(pv & 0xFFFFu);
  }
}

// --- LDS GEMM + al epilogue: A[n,128]@W[128,OUTC] -> Hout(f16), alS/alD(f32)
template <int BROWS, int BCOLS, int TR, int H, typename AT>
__global__ __launch_bounds__(256) void gemm_al_kernel(const AT* __restrict__ A,
                                                      const float* __restrict__ W,
                                                      const float* __restrict__ a_src,
                                                      const float* __restrict__ a_dst,
                                                      __half* __restrict__ Hout,
                                                      float* __restrict__ alS,
                                                      float* __restrict__ alD,
                                                      int n, int OUTC) {
  constexpr int TC = 4;
  constexpr int CG = BCOLS / TC;   // col groups
  constexpr int RG = BROWS / TR;   // row groups
  static_assert(CG * RG == 256, "256 threads");
  constexpr int AP = 132;          // padded A row stride (floats)
  constexpr bool A16 = (sizeof(AT) == 2);

  __shared__ __align__(16) float A_lds[BROWS * AP];
  __shared__ __align__(16) float W_lds[128 * BCOLS];

  const int r0 = blockIdx.x * BROWS;
  const int cb = blockIdx.y * BCOLS;
  const int t = threadIdx.x;

  if constexpr (!A16) {
#pragma unroll
    for (int i = 0; i < BROWS / 8; ++i) {
      int slot = t + i * 256;
      int r = slot >> 5;
      int kq = slot & 31;
      float4 v = make_float4(0.f, 0.f, 0.f, 0.f);
      if (r0 + r < n) v = *(const float4*)((const float*)A + (size_t)(r0 + r) * 128 + kq * 4);
      *(float4*)&A_lds[r * AP + kq * 4] = v;
    }
  } else {
#pragma unroll
    for (int i = 0; i < BROWS / 16; ++i) {
      int slot = t + i * 256;
      int r = slot >> 4;        // 16 8-half (16B) chunks per 128-half row
      int q = slot & 15;
      uint4 raw = make_uint4(0u, 0u, 0u, 0u);   // R8 fix: 16B, was uint2 (8B)
      if (r0 + r < n) raw = *(const uint4*)((const __half*)A + (size_t)(r0 + r) * 128 + q * 8);
      const __half2* hp = (const __half2*)&raw;
      float2 f0 = __half22float2(hp[0]);
      float2 f1 = __half22float2(hp[1]);
      float2 f2 = __half22float2(hp[2]);
      float2 f3 = __half22float2(hp[3]);
      *(float4*)&A_lds[r * AP + q * 8] = make_float4(f0.x, f0.y, f1.x, f1.y);
      *(float4*)&A_lds[r * AP + q * 8 + 4] = make_float4(f2.x, f2.y, f3.x, f3.y);
    }
  }
#pragma unroll
  for (int i = 0; i < BCOLS / 8; ++i) {
    int slot = t + i * 256;
    int k = slot / (BCOLS / 4);
    int cq = slot % (BCOLS / 4);
    float4 v = *(const float4*)(W + (size_t)k * OUTC + cb + cq * 4);
    *(float4*)&W_lds[k * BCOLS + cq * 4] = v;
  }
  __syncthreads();

  const int cg = t % CG;
  const int rg = t / CG;

  float acc[TR][TC];
#pragma unroll
  for (int i = 0; i < TR; ++i)
#pragma unroll
    for (int j = 0; j < TC; ++j) acc[i][j] = 0.f;

  for (int k4 = 0; k4 < 32; ++k4) {
    float av[TR][4];
#pragma unroll
    for (int i = 0; i < TR; ++i) {
      float4 a4 = *(const float4*)&A_lds[(rg * TR + i) * AP + k4 * 4];
      av[i][0] = a4.x; av[i][1] = a4.y; av[i][2] = a4.z; av[i][3] = a4.w;
    }
#pragma unroll
    for (int kk = 0; kk < 4; ++kk) {
      float4 w4 = *(const float4*)&W_lds[(k4 * 4 + kk) * BCOLS + cg * TC];
#pragma unroll
      for (int i = 0; i < TR; ++i) {
        acc[i][0] = fmaf(av[i][kk], w4.x, acc[i][0]);
        acc[i][1] = fmaf(av[i][kk], w4.y, acc[i][1]);
        acc[i][2] = fmaf(av[i][kk], w4.z, acc[i][2]);
        acc[i][3] = fmaf(av[i][kk], w4.w, acc[i][3]);
      }
    }
  }

  // ---- write f16 h ----
#pragma unroll
  for (int i = 0; i < TR; ++i) {
    int r = r0 + rg * TR + i;
    if (r >= n) continue;
    __half2 lo = __floats2half2_rn(acc[i][0], acc[i][1]);
    __half2 hi = __floats2half2_rn(acc[i][2], acc[i][3]);
    uint2 pk;
    pk.x = *(const unsigned*)&lo;
    pk.y = *(const unsigned*)&hi;
    *(uint2*)(Hout + (size_t)r * OUTC + cb + cg * TC) = pk;
  }

  // ---- al epilogue: reduce over the 8 col-group lanes of each head ----
  const int head = (cb + cg * TC) >> 5;
  const int cLoc = (cg & 7) * 4;
  float as_c[4], ad_c[4];
#pragma unroll
  for (int j = 0; j < 4; ++j) {
    as_c[j] = a_src[head * 32 + cLoc + j];
    ad_c[j] = a_dst[head * 32 + cLoc + j];
  }
#pragma unroll
  for (int i = 0; i < TR; ++i) {
    float ps = acc[i][0] * as_c[0] + acc[i][1] * as_c[1] +
               acc[i][2] * as_c[2] + acc[i][3] * as_c[3];
    float pd = acc[i][0] * ad_c[0] + acc[i][1] * ad_c[1] +
               acc[i][2] * ad_c[2] + acc[i][3] * ad_c[3];
#pragma unroll
    for (int off = 1; off < 8; off <<= 1) {
      ps += __shfl_xor(ps, off);
      pd += __shfl_xor(pd, off);
    }
    if ((cg & 7) == 0) {
      int r = r0 + rg * TR + i;
      if (r < n) {
        alS[(size_t)r * H + head] = ps;
        alD[(size_t)r * H + head] = pd;
      }
    }
  }
}

// --- agg: staged exp weights (no max-subtract), byte-offset f16 gather ------
template <int H, bool BN, typename OutT>
__global__ __launch_bounds__(256) void agg_kernel(
    const int* __restrict__ row_ptr, const int* __restrict__ csr_src,
    const float* __restrict__ alS, const float* __restrict__ alD,
    const __half* __restrict__ hfeat, const float* __restrict__ bias,
    const float* __restrict__ bnw, const float* __restrict__ bnb,
    const float* __restrict__ bnm, const float* __restrict__ bnv,
    OutT* __restrict__ out, int n) {
  constexpr int LPN = (H == 4) ? 64 : 32;     // lanes per node
  constexpr int NPB = 256 / LPN;              // node slots per block
  constexpr int KCAP = 96;                    // staged-edge capacity
  constexpr int RSH = (H == 4) ? 8 : 6;       // log2(row bytes): 256B / 64B

  __shared__ __align__(16) float sW[NPB][KCAP * H];
  __shared__ int sOff[NPB][KCAP];

  const int slot = threadIdx.x / LPN;
  const int sl = threadIdx.x % LPN;
  const int v = blockIdx.x * NPB + slot;
  const bool active = v < n;
  const char* hb = (const char*)hfeat;

  int rs = 0, re = 0;
  if (active) { rs = row_ptr[v]; re = row_ptr[v + 1]; }
  const int deg = re - rs;
  const int degS = deg < KCAP ? deg : KCAP;

  if constexpr (H == 4) {
    float4 ad4 = make_float4(0.f, 0.f, 0.f, 0.f);
    if (active) ad4 = *(const float4*)(alD + (size_t)v * 4);
    float den0 = 0.f, den1 = 0.f, den2 = 0.f, den3 = 0.f;
    for (int k = sl; k < degS; k += 64) {
      int s = csr_src[rs + k];
      sOff[slot][k] = s << RSH;
      float4 a4 = *(const float4*)(alS + (size_t)s * 4);
      float u0 = expw(lrelu02(a4.x + ad4.x));
      float u1 = expw(lrelu02(a4.y + ad4.y));
      float u2 = expw(lrelu02(a4.z + ad4.z));
      float u3 = expw(lrelu02(a4.w + ad4.w));
      ((float4*)&sW[slot][0])[k] = make_float4(u0, u1, u2, u3);
      den0 += u0; den1 += u1; den2 += u2; den3 += u3;
    }
#pragma unroll
    for (int off = 32; off >= 1; off >>= 1) {
      den0 += __shfl_xor(den0, off);
      den1 += __shfl_xor(den1, off);
      den2 += __shfl_xor(den2, off);
      den3 += __shfl_xor(den3, off);
    }

    const int c = 2 * sl;          // channels c, c+1
    const int h = sl >> 4;         // head 0..3
    const unsigned cb2 = (unsigned)(c * 2);   // channel byte offset
    float2 acc = make_float2(0.f, 0.f);
    int j = 0;
    for (; j + 4 <= degS; j += 4) {
      unsigned o0 = (unsigned)sOff[slot][j + 0] + cb2;
      unsigned o1 = (unsigned)sOff[slot][j + 1] + cb2;
      unsigned o2 = (unsigned)sOff[slot][j + 2] + cb2;
      unsigned o3 = (unsigned)sOff[slot][j + 3] + cb2;
      float w0 = sW[slot][(j + 0) * 4 + h];
      float w1 = sW[slot][(j + 1) * 4 + h];
      float w2 = sW[slot][(j + 2) * 4 + h];
      float w3 = sW[slot][(j + 3) * 4 + h];
      float2 f0 = __half22float2(*(const __half2*)(hb + o0));
      float2 f1 = __half22float2(*(const __half2*)(hb + o1));
      float2 f2 = __half22float2(*(const __half2*)(hb + o2));
      float2 f3 = __half22float2(*(const __half2*)(hb + o3));
      acc.x = fmaf(w0, f0.x, acc.x); acc.y = fmaf(w0, f0.y, acc.y);
      acc.x = fmaf(w1, f1.x, acc.x); acc.y = fmaf(w1, f1.y, acc.y);
      acc.x = fmaf(w2, f2.x, acc.x); acc.y = fmaf(w2, f2.y, acc.y);
      acc.x = fmaf(w3, f3.x, acc.x); acc.y = fmaf(w3, f3.y, acc.y);
    }
    for (; j < degS; ++j) {
      unsigned o = (unsigned)sOff[slot][j] + cb2;
      float w = sW[slot][j * 4 + h];
      float2 f = __half22float2(*(const __half2*)(hb + o));
      acc.x = fmaf(w, f.x, acc.x); acc.y = fmaf(w, f.y, acc.y);
    }
    float den = (h == 0) ? den0 : (h == 1) ? den1 : (h == 2) ? den2 : den3;
    if (deg > KCAP) {  // cold fallback
      float adh = alD[(size_t)v * 4 + h];
      for (int e = rs + KCAP; e < re; ++e) {
        int s = csr_src[e];
        float u = expw(lrelu02(alS[(size_t)s * 4 + h] + adh));
        den += u;
        float2 f = __half22float2(*(const __half2*)(hb + ((unsigned)(s << RSH) + cb2)));
        acc.x = fmaf(u, f.x, acc.x); acc.y = fmaf(u, f.y, acc.y);
      }
    }
    if (active) {
      float inv = 1.f / (den + 1e-16f);
      float2 b2v = *(const float2*)(bias + c);
      float g0 = acc.x * inv + b2v.x;
      float g1 = acc.y * inv + b2v.y;
      if constexpr (BN) {
        float2 bw = *(const float2*)(bnw + c);
        float2 bb = *(const float2*)(bnb + c);
        float2 bm = *(const float2*)(bnm + c);
        float2 bv = *(const float2*)(bnv + c);
        g0 = (g0 - bm.x) * (bw.x * rsqrtf(bv.x + 1e-5f)) + bb.x;
        g1 = (g1 - bm.y) * (bw.y * rsqrtf(bv.y + 1e-5f)) + bb.y;
        g0 = fmaxf(g0, 0.f);
        g1 = fmaxf(g1, 0.f);
      }
      if constexpr (sizeof(OutT) == 2) {
        __half2 o2 = __floats2half2_rn(g0, g1);
        *(__half2*)((__half*)out + (size_t)v * 128 + c) = o2;
      } else {
        *(float2*)((float*)out + (size_t)v * 128 + c) = make_float2(g0, g1);
      }
    }
  } else {  // H == 1, C == 32
    float ad = active ? alD[v] : 0.f;
    float den = 0.f;
    for (int k = sl; k < degS; k += 32) {
      int s = csr_src[rs + k];
      sOff[slot][k] = s << RSH;
      float u = expw(lrelu02(alS[s] + ad));
      sW[slot][k] = u;
      den += u;
    }
#pragma unroll
    for (int off = 16; off >= 1; off >>= 1) den += __shfl_xor(den, off);

    const int c = sl;
    const unsigned cb2 = (unsigned)(c * 2);
    float acc = 0.f;
    int j = 0;
    for (; j + 4 <= degS; j += 4) {
      unsigned o0 = (unsigned)sOff[slot][j + 0] + cb2;
      unsigned o1 = (unsigned)sOff[slot][j + 1] + cb2;
      unsigned o2 = (unsigned)sOff[slot][j + 2] + cb2;
      unsigned o3 = (unsigned)sOff[slot][j + 3] + cb2;
      float w0 = sW[slot][j + 0], w1 = sW[slot][j + 1];
      float w2 = sW[slot][j + 2], w3 = sW[slot][j + 3];
      float f0 = __half2float(*(const __half*)(hb + o0));
      float f1 = __half2float(*(const __half*)(hb + o1));
      float f2 = __half2float(*(const __half*)(hb + o2));
      float f3 = __half2float(*(const __half*)(hb + o3));
      acc = fmaf(w0, f0, acc); acc = fmaf(w1, f1, acc);
      acc = fmaf(w2, f2, acc); acc = fmaf(w3, f3, acc);
    }
    for (; j < degS; ++j) {
      unsigned o = (unsigned)sOff[slot][j] + cb2;
      float w = sW[slot][j];
      acc = fmaf(w, __half2float(*(const __half*)(hb + o)), acc);
    }
    if (deg > KCAP) {
      for (int e = rs + KCAP; e < re; ++e) {
        int s = csr_src[e];
        float u = expw(lrelu02(alS[s] + ad));
        den += u;
        acc = fmaf(u, __half2float(*(const __half*)(hb + ((unsigned)(s << RSH) + cb2))), acc);
      }
    }
    if (active) {
      ((float*)out)[(size_t)v * 32 + c] = acc / (den + 1e-16f) + bias[c];
    }
  }
}

// ---------------------------------------------------------------------------
extern "C" void kernel_launch(void* const* d_in, const int* in_sizes, int n_in,
                              void* d_out, int out_size, void* d_ws, size_t ws_size,
                              hipStream_t stream) {
  const float* x = (const float*)d_in[0];
  const void* ei = d_in[1];
  const float* w1 = (const float*)d_in[2];
  const float* as1 = (const float*)d_in[3];
  const float* ad1 = (const float*)d_in[4];
  const float* b1 = (const float*)d_in[5];
  const float* bn1w = (const float*)d_in[6];
  const float* bn1b = (const float*)d_in[7];
  const float* bn1m = (const float*)d_in[8];
  const float* bn1v = (const float*)d_in[9];
  const float* w2 = (const float*)d_in[10];
  const float* as2 = (const float*)d_in[11];
  const float* ad2 = (const float*)d_in[12];
  const float* b2 = (const float*)d_in[13];
  const float* bn2w = (const float*)d_in[14];
  const float* bn2b = (const float*)d_in[15];
  const float* bn2m = (const float*)d_in[16];
  const float* bn2v = (const float*)d_in[17];
  const float* w3 = (const float*)d_in[18];
  const float* as3 = (const float*)d_in[19];
  const float* ad3 = (const float*)d_in[20];
  const float* b3 = (const float*)d_in[21];

  const int N = in_sizes[0] / 128;
  const int E = in_sizes[1] / 2;
  const int nbk = (N + 127) / 128;
  const int chunk = (E + NBCHUNK - 1) / NBCHUNK;

  // workspace layout (256B aligned slices)
  char* base = (char*)d_ws;
  size_t off = 0;
  auto alloc = [&](size_t bytes) {
    void* p = base + off;
    off = (off + bytes + 255) & ~(size_t)255;
    return p;
  };
  int* flag = (int*)alloc(4);
  int* counts = (int*)alloc((size_t)NBCHUNK * nbk * 4);
  int* T = (int*)alloc((size_t)nbk * 4);
  int* EB = (int*)alloc((size_t)(nbk + 1) * 4);
  unsigned* binned = (unsigned*)alloc((size_t)E * 4);
  int* row_ptr = (int*)alloc((size_t)(N + 1) * 4);
  int* csr_src = (int*)alloc((size_t)(E + N) * 4);
  __half* hbuf = (__half*)alloc((size_t)N * 128 * 2);
  __half* gbuf = (__half*)alloc((size_t)N * 128 * 2);
  float* alS = (float*)alloc((size_t)N * 4 * 4);
  float* alD = (float*)alloc((size_t)N * 4 * 4);
  (void)ws_size;

  // ---- CSR build (no global atomics) ----
  detect_kernel<<<1, 64, 0, stream>>>((const unsigned*)ei, flag);
  bcount_kernel<<<NBCHUNK, 256, 0, stream>>>(ei, E, flag, counts, nbk, chunk);
  bscanT_kernel<<<nbk, NBCHUNK, 0, stream>>>(counts, T, nbk);
  bscanE_kernel<<<1, 64, 0, stream>>>(T, EB, nbk);
  bemit_kernel<<<NBCHUNK, 256, 0, stream>>>(ei, E, flag, counts, EB, nbk, chunk, binned);
  bscatter2_kernel<<<nbk, 256, 0, stream>>>(binned, EB, row_ptr, csr_src, N, E);

  const int rowBlocks = (N + 63) / 64;

  // ---- layer 1 ----
  gemm_al_kernel<64, 64, 4, 4, float><<<dim3(rowBlocks, 2), 256, 0, stream>>>(
      x, w1, as1, ad1, hbuf, alS, alD, N, 128);
  agg_kernel<4, true, __half><<<(N + 3) / 4, 256, 0, stream>>>(
      row_ptr, csr_src, alS, alD, hbuf, b1, bn1w, bn1b, bn1m, bn1v, gbuf, N);
  // ---- layer 2 ----
  gemm_al_kernel<64, 64, 4, 4, __half><<<dim3(rowBlocks, 2), 256, 0, stream>>>(
      gbuf, w2, as2, ad2, hbuf, alS, alD, N, 128);
  agg_kernel<4, true, __half><<<(N + 3) / 4, 256, 0, stream>>>(
      row_ptr, csr_src, alS, alD, hbuf, b2, bn2w, bn2b, bn2m, bn2v, gbuf, N);
  // ---- layer 3 ----
  gemm_al_kernel<64, 32, 2, 1, __half><<<dim3(rowBlocks, 1), 256, 0, stream>>>(
      gbuf, w3, as3, ad3, hbuf, alS, alD, N, 32);
  agg_kernel<1, false, float><<<(N + 7) / 8, 256, 0, stream>>>(
      row_ptr, csr_src, alS, alD, hbuf, b3, nullptr, nullptr, nullptr, nullptr,
      (float*)d_out, N);
}

// Round 10
// 199.222 us; speedup vs baseline: 2.6721x; 1.1175x over previous
//
#include <hip/hip_runtime.h>
#include <hip/hip_fp16.h>
#include <cstdint>

// ---------------------------------------------------------------------------
// EpilepsyGNN: 3-layer GAT (4 heads x 32 -> 4x32 -> 1x32), BN(eval)+ReLU
// CSR build: bucketed two-phase scatter, zero global atomics (R6/R7 design).
// GEMM: MFMA f16 (v_mfma_f32_16x16x32_f16), LDS-staged A + W^T, f32 accum,
// al logits computed from f32 accumulators in the epilogue.
// agg: no-max softmax (scale-invariant, clamp-guarded), exp hoisted to
// staging, pure f16 gather+fmaf inner loop. Activations f16, math f32.
// ---------------------------------------------------------------------------

#define NBCHUNK 128   // edge chunks for bucket counting/emission
#define MAXBK 512     // max buckets of 128 nodes (N <= 65536; packing needs it)

typedef _Float16 f16x8 __attribute__((ext_vector_type(8)));
typedef float f32x4 __attribute__((ext_vector_type(4)));

__device__ __forceinline__ float lrelu02(float x) {
  return x > 0.f ? x : 0.2f * x;
}

__device__ __forceinline__ float expw(float x) {
  return __expf(fminf(x, 80.f));   // clamp is a no-op for this data; inf guard
}

// --- edge dtype detection: int64 (little-endian) has all-odd words == 0 -----
__global__ void detect_kernel(const unsigned* __restrict__ ei, int* __restrict__ flag) {
  int lane = threadIdx.x;                 // one wave
  unsigned w = ei[2 * lane + 1];          // odd words 1,3,...,127
  unsigned long long nz = __ballot(w != 0u);
  if (lane == 0) *flag = (nz == 0ull) ? 1 : 0;
}

// --- phase 1: per-chunk LDS histogram of dst buckets ------------------------
__global__ __launch_bounds__(256) void bcount_kernel(const void* __restrict__ ei, int E,
                                                     const int* __restrict__ flag,
                                                     int* __restrict__ counts,
                                                     int nbk, int chunk) {
  __shared__ int hist[MAXBK];
  for (int i = threadIdx.x; i < nbk; i += 256) hist[i] = 0;
  __syncthreads();
  int lo = blockIdx.x * chunk;
  int hi = lo + chunk; if (hi > E) hi = E;
  const bool is64 = (*flag) != 0;
  for (int e = lo + threadIdx.x; e < hi; e += 256) {
    int d = is64 ? (int)((const long long*)ei)[(size_t)E + e] : ((const int*)ei)[E + e];
    atomicAdd(&hist[d >> 7], 1);
  }
  __syncthreads();
  for (int i = threadIdx.x; i < nbk; i += 256)
    counts[(size_t)blockIdx.x * nbk + i] = hist[i];
}

// --- phase 2a: per-bucket exclusive scan over chunks; totals -> T -----------
__global__ void bscanT_kernel(int* __restrict__ counts, int* __restrict__ T, int nbk) {
  int b = blockIdx.x;
  int t = threadIdx.x;           // NBCHUNK = 128 threads
  int lane = t & 63;
  int v = counts[(size_t)t * nbk + b];
  int inc = v;
#pragma unroll
  for (int off = 1; off < 64; off <<= 1) {
    int u = __shfl_up(inc, off);
    if (lane >= off) inc += u;
  }
  __shared__ int w0;
  if (t == 63) w0 = inc;
  __syncthreads();
  int wb = (t >= 64) ? w0 : 0;
  counts[(size_t)t * nbk + b] = wb + inc - v;   // chunk-exclusive, bucket-local
  if (t == 127) T[b] = wb + inc;                // bucket edge total
}

// --- phase 2b: single-wave exclusive scan of bucket totals -> EB ------------
__global__ void bscanE_kernel(const int* __restrict__ T, int* __restrict__ EB, int nbk) {
  int lane = threadIdx.x;  // 64 threads
  int carry = 0;
  for (int start = 0; start < nbk; start += 64) {
    int i = start + lane;
    int v = (i < nbk) ? T[i] : 0;
    int inc = v;
#pragma unroll
    for (int off = 1; off < 64; off <<= 1) {
      int u = __shfl_up(inc, off);
      if (lane >= off) inc += u;
    }
    if (i < nbk) EB[i] = inc - v + carry;
    carry += __shfl(inc, 63);
  }
  if (lane == 0) EB[nbk] = carry;
}

// --- phase 3: emit packed (dloc<<16 | src) bucket-contiguously --------------
__global__ __launch_bounds__(256) void bemit_kernel(const void* __restrict__ ei, int E,
                                                    const int* __restrict__ flag,
                                                    const int* __restrict__ counts,
                                                    const int* __restrict__ EB,
                                                    int nbk, int chunk,
                                                    unsigned* __restrict__ binned) {
  __shared__ int cur[MAXBK];
  for (int i = threadIdx.x; i < nbk; i += 256)
    cur[i] = counts[(size_t)blockIdx.x * nbk + i] + EB[i];
  __syncthreads();
  int lo = blockIdx.x * chunk;
  int hi = lo + chunk; if (hi > E) hi = E;
  const bool is64 = (*flag) != 0;
  for (int e = lo + threadIdx.x; e < hi; e += 256) {
    int s, d;
    if (is64) {
      const long long* p = (const long long*)ei;
      s = (int)p[e];
      d = (int)p[(size_t)E + e];
    } else {
      const int* p = (const int*)ei;
      s = p[e];
      d = p[E + e];
    }
    int pos = atomicAdd(&cur[d >> 7], 1);   // LDS atomic: cheap
    binned[pos] = ((unsigned)(d & 127) << 16) | (unsigned)s;   // N <= 65536
  }
}

// --- phase 4: per-bucket histogram -> row_ptr + self-loops + scatter --------
__global__ __launch_bounds__(256) void bscatter2_kernel(const unsigned* __restrict__ binned,
                                                        const int* __restrict__ EB,
                                                        int* __restrict__ row_ptr,
                                                        int* __restrict__ csr_src,
                                                        int n, int E) {
  __shared__ int hist[128];
  __shared__ int cur[128];
  __shared__ int w0s;
  const int b = blockIdx.x;
  const int t = threadIdx.x;
  const int bb = b << 7;
  if (t < 128) hist[t] = 0;
  __syncthreads();
  const int lo = EB[b], hi = EB[b + 1];
  for (int i = lo + t; i < hi; i += 256)
    atomicAdd(&hist[binned[i] >> 16], 1);
  __syncthreads();
  int lane = t & 63;
  int v = (t < 128) ? hist[t] : 0;
  int inc = v;
#pragma unroll
  for (int off = 1; off < 64; off <<= 1) {
    int u = __shfl_up(inc, off);
    if (lane >= off) inc += u;
  }
  if (t == 63) w0s = inc;
  __syncthreads();
  int exc = ((t >= 64 && t < 128) ? w0s : 0) + inc - v;
  if (t < 128 && bb + t < n) {
    int rp = EB[b] + bb + t + exc;   // edges-before-node + self-loops-before
    row_ptr[bb + t] = rp;
    csr_src[rp] = bb + t;            // self loop at slot 0
    cur[t] = rp + 1;
  }
  if (b == 0 && t == 0) row_ptr[n] = E + n;
  __syncthreads();
  for (int i = lo + t; i < hi; i += 256) {
    unsigned pv = binned[i];
    int pos = atomicAdd(&cur[pv >> 16], 1);
    csr_src[pos] = (int)(pv & 0xFFFFu);
  }
}

// --- W[128][OUTC] f32 -> Wt[c][k] f16 (tiny; once per layer) ----------------
__global__ void wcvt_kernel(const float* __restrict__ W, _Float16* __restrict__ Wt,
                            int OUTC) {
  int idx = blockIdx.x * 256 + threadIdx.x;
  if (idx >= 128 * OUTC) return;
  int k = idx / OUTC, c = idx % OUTC;
  Wt[(size_t)c * 128 + k] = (_Float16)W[idx];
}

// --- MFMA GEMM + al epilogue: A[n,128]@W[128,OUTC] -> H(f16), alS/alD(f32) --
// 4 waves/block; wave w owns rows [r0+16w, r0+16w+16), all OUTC cols.
// Fragment maps (gfx950 16x16x32_f16): A/B k=(lane>>4)*8+j, row/col=lane&15;
// C/D col=lane&15, row=(lane>>4)*4+reg.
template <int OUTC, int H, typename AT>
__global__ __launch_bounds__(256) void mfma_gemm_al_kernel(
    const AT* __restrict__ A, const _Float16* __restrict__ Wt,
    const float* __restrict__ a_src, const float* __restrict__ a_dst,
    __half* __restrict__ Hout, float* __restrict__ alS, float* __restrict__ alD,
    int n) {
  constexpr int NT = OUTC / 16;    // col tiles per wave (8 or 2)
  constexpr int APH = 136;         // LDS row stride in halves (16B-aligned rows)

  __shared__ __align__(16) _Float16 A_lds[64 * APH];
  __shared__ __align__(16) _Float16 W_lds[OUTC * APH];

  const int t = threadIdx.x;
  const int r0 = blockIdx.x * 64;

  // ---- stage A (convert f32->f16 for layer 1) ----
  if constexpr (sizeof(AT) == 4) {
#pragma unroll
    for (int i = 0; i < 8; ++i) {
      int slot = t + i * 256;
      int r = slot >> 5, q = slot & 31;     // q: float4 index along k
      float4 v = make_float4(0.f, 0.f, 0.f, 0.f);
      if (r0 + r < n) v = *(const float4*)((const float*)A + (size_t)(r0 + r) * 128 + q * 4);
      __half2 p0 = __floats2half2_rn(v.x, v.y);
      __half2 p1 = __floats2half2_rn(v.z, v.w);
      uint2 pk;
      pk.x = *(unsigned*)&p0;
      pk.y = *(unsigned*)&p1;
      *(uint2*)&A_lds[r * APH + q * 4] = pk;
    }
  } else {
#pragma unroll
    for (int i = 0; i < 4; ++i) {
      int slot = t + i * 256;
      int r = slot >> 4, q = slot & 15;     // q: 8-half (16B) chunk
      uint4 raw = make_uint4(0u, 0u, 0u, 0u);
      if (r0 + r < n) raw = *(const uint4*)((const __half*)A + (size_t)(r0 + r) * 128 + q * 8);
      *(uint4*)&A_lds[r * APH + q * 8] = raw;
    }
  }
  // ---- stage Wt (f16, already transposed) ----
#pragma unroll
  for (int i = 0; i < OUTC / 16; ++i) {
    int slot = t + i * 256;
    int c = slot >> 4, q = slot & 15;
    uint4 raw = *(const uint4*)(Wt + (size_t)c * 128 + q * 8);
    *(uint4*)&W_lds[c * APH + q * 8] = raw;
  }
  __syncthreads();

  const int w = t >> 6;
  const int lane = t & 63;
  const int lrow = lane & 15;
  const int lk = lane >> 4;

  f32x4 acc[NT];
#pragma unroll
  for (int i = 0; i < NT; ++i) acc[i] = (f32x4){0.f, 0.f, 0.f, 0.f};

#pragma unroll
  for (int kc = 0; kc < 4; ++kc) {
    f16x8 a = *(const f16x8*)&A_lds[(w * 16 + lrow) * APH + kc * 32 + lk * 8];
#pragma unroll
    for (int ct = 0; ct < NT; ++ct) {
      f16x8 b = *(const f16x8*)&W_lds[(ct * 16 + lrow) * APH + kc * 32 + lk * 8];
      acc[ct] = __builtin_amdgcn_mfma_f32_16x16x32_f16(a, b, acc[ct], 0, 0, 0);
    }
  }

  // ---- H stores (f16) ----
  const int rbase = r0 + w * 16 + lk * 4;
#pragma unroll
  for (int ct = 0; ct < NT; ++ct) {
#pragma unroll
    for (int j = 0; j < 4; ++j) {
      int r = rbase + j;
      if (r < n) Hout[(size_t)r * OUTC + ct * 16 + lrow] = __float2half(acc[ct][j]);
    }
  }

  // ---- al epilogue from f32 accumulators ----
#pragma unroll
  for (int h = 0; h < H; ++h) {
    float as0 = a_src[h * 32 + lrow], as1 = a_src[h * 32 + 16 + lrow];
    float ad0 = a_dst[h * 32 + lrow], ad1 = a_dst[h * 32 + 16 + lrow];
#pragma unroll
    for (int j = 0; j < 4; ++j) {
      float ps = acc[2 * h][j] * as0 + acc[2 * h + 1][j] * as1;
      float pd = acc[2 * h][j] * ad0 + acc[2 * h + 1][j] * ad1;
#pragma unroll
      for (int off = 1; off < 16; off <<= 1) {
        ps += __shfl_xor(ps, off);
        pd += __shfl_xor(pd, off);
      }
      if (lrow == 0) {
        int r = rbase + j;
        if (r < n) {
          alS[(size_t)r * H + h] = ps;
          alD[(size_t)r * H + h] = pd;
        }
      }
    }
  }
}

// --- agg: staged exp weights (no max-subtract), byte-offset f16 gather ------
template <int H, bool BN, typename OutT>
__global__ __launch_bounds__(256) void agg_kernel(
    const int* __restrict__ row_ptr, const int* __restrict__ csr_src,
    const float* __restrict__ alS, const float* __restrict__ alD,
    const __half* __restrict__ hfeat, const float* __restrict__ bias,
    const float* __restrict__ bnw, const float* __restrict__ bnb,
    const float* __restrict__ bnm, const float* __restrict__ bnv,
    OutT* __restrict__ out, int n) {
  constexpr int LPN = (H == 4) ? 64 : 32;     // lanes per node
  constexpr int NPB = 256 / LPN;              // node slots per block
  constexpr int KCAP = 96;                    // staged-edge capacity
  constexpr int RSH = (H == 4) ? 8 : 6;       // log2(row bytes): 256B / 64B

  __shared__ __align__(16) float sW[NPB][KCAP * H];
  __shared__ int sOff[NPB][KCAP];

  const int slot = threadIdx.x / LPN;
  const int sl = threadIdx.x % LPN;
  const int v = blockIdx.x * NPB + slot;
  const bool active = v < n;
  const char* hb = (const char*)hfeat;

  int rs = 0, re = 0;
  if (active) { rs = row_ptr[v]; re = row_ptr[v + 1]; }
  const int deg = re - rs;
  const int degS = deg < KCAP ? deg : KCAP;

  if constexpr (H == 4) {
    float4 ad4 = make_float4(0.f, 0.f, 0.f, 0.f);
    if (active) ad4 = *(const float4*)(alD + (size_t)v * 4);
    float den0 = 0.f, den1 = 0.f, den2 = 0.f, den3 = 0.f;
    for (int k = sl; k < degS; k += 64) {
      int s = csr_src[rs + k];
      sOff[slot][k] = s << RSH;
      float4 a4 = *(const float4*)(alS + (size_t)s * 4);
      float u0 = expw(lrelu02(a4.x + ad4.x));
      float u1 = expw(lrelu02(a4.y + ad4.y));
      float u2 = expw(lrelu02(a4.z + ad4.z));
      float u3 = expw(lrelu02(a4.w + ad4.w));
      ((float4*)&sW[slot][0])[k] = make_float4(u0, u1, u2, u3);
      den0 += u0; den1 += u1; den2 += u2; den3 += u3;
    }
#pragma unroll
    for (int off = 32; off >= 1; off >>= 1) {
      den0 += __shfl_xor(den0, off);
      den1 += __shfl_xor(den1, off);
      den2 += __shfl_xor(den2, off);
      den3 += __shfl_xor(den3, off);
    }

    const int c = 2 * sl;          // channels c, c+1
    const int h = sl >> 4;         // head 0..3
    const unsigned cb2 = (unsigned)(c * 2);   // channel byte offset
    float2 acc = make_float2(0.f, 0.f);
    int j = 0;
    for (; j + 4 <= degS; j += 4) {
      unsigned o0 = (unsigned)sOff[slot][j + 0] + cb2;
      unsigned o1 = (unsigned)sOff[slot][j + 1] + cb2;
      unsigned o2 = (unsigned)sOff[slot][j + 2] + cb2;
      unsigned o3 = (unsigned)sOff[slot][j + 3] + cb2;
      float w0 = sW[slot][(j + 0) * 4 + h];
      float w1 = sW[slot][(j + 1) * 4 + h];
      float w2 = sW[slot][(j + 2) * 4 + h];
      float w3 = sW[slot][(j + 3) * 4 + h];
      float2 f0 = __half22float2(*(const __half2*)(hb + o0));
      float2 f1 = __half22float2(*(const __half2*)(hb + o1));
      float2 f2 = __half22float2(*(const __half2*)(hb + o2));
      float2 f3 = __half22float2(*(const __half2*)(hb + o3));
      acc.x = fmaf(w0, f0.x, acc.x); acc.y = fmaf(w0, f0.y, acc.y);
      acc.x = fmaf(w1, f1.x, acc.x); acc.y = fmaf(w1, f1.y, acc.y);
      acc.x = fmaf(w2, f2.x, acc.x); acc.y = fmaf(w2, f2.y, acc.y);
      acc.x = fmaf(w3, f3.x, acc.x); acc.y = fmaf(w3, f3.y, acc.y);
    }
    for (; j < degS; ++j) {
      unsigned o = (unsigned)sOff[slot][j] + cb2;
      float w = sW[slot][j * 4 + h];
      float2 f = __half22float2(*(const __half2*)(hb + o));
      acc.x = fmaf(w, f.x, acc.x); acc.y = fmaf(w, f.y, acc.y);
    }
    float den = (h == 0) ? den0 : (h == 1) ? den1 : (h == 2) ? den2 : den3;
    if (deg > KCAP) {  // cold fallback
      float adh = alD[(size_t)v * 4 + h];
      for (int e = rs + KCAP; e < re; ++e) {
        int s = csr_src[e];
        float u = expw(lrelu02(alS[(size_t)s * 4 + h] + adh));
        den += u;
        float2 f = __half22float2(*(const __half2*)(hb + ((unsigned)(s << RSH) + cb2)));
        acc.x = fmaf(u, f.x, acc.x); acc.y = fmaf(u, f.y, acc.y);
      }
    }
    if (active) {
      float inv = 1.f / (den + 1e-16f);
      float2 b2v = *(const float2*)(bias + c);
      float g0 = acc.x * inv + b2v.x;
      float g1 = acc.y * inv + b2v.y;
      if constexpr (BN) {
        float2 bw = *(const float2*)(bnw + c);
        float2 bb = *(const float2*)(bnb + c);
        float2 bm = *(const float2*)(bnm + c);
        float2 bv = *(const float2*)(bnv + c);
        g0 = (g0 - bm.x) * (bw.x * rsqrtf(bv.x + 1e-5f)) + bb.x;
        g1 = (g1 - bm.y) * (bw.y * rsqrtf(bv.y + 1e-5f)) + bb.y;
        g0 = fmaxf(g0, 0.f);
        g1 = fmaxf(g1, 0.f);
      }
      if constexpr (sizeof(OutT) == 2) {
        __half2 o2 = __floats2half2_rn(g0, g1);
        *(__half2*)((__half*)out + (size_t)v * 128 + c) = o2;
      } else {
        *(float2*)((float*)out + (size_t)v * 128 + c) = make_float2(g0, g1);
      }
    }
  } else {  // H == 1, C == 32
    float ad = active ? alD[v] : 0.f;
    float den = 0.f;
    for (int k = sl; k < degS; k += 32) {
      int s = csr_src[rs + k];
      sOff[slot][k] = s << RSH;
      float u = expw(lrelu02(alS[s] + ad));
      sW[slot][k] = u;
      den += u;
    }
#pragma unroll
    for (int off = 16; off >= 1; off >>= 1) den += __shfl_xor(den, off);

    const int c = sl;
    const unsigned cb2 = (unsigned)(c * 2);
    float acc = 0.f;
    int j = 0;
    for (; j + 4 <= degS; j += 4) {
      unsigned o0 = (unsigned)sOff[slot][j + 0] + cb2;
      unsigned o1 = (unsigned)sOff[slot][j + 1] + cb2;
      unsigned o2 = (unsigned)sOff[slot][j + 2] + cb2;
      unsigned o3 = (unsigned)sOff[slot][j + 3] + cb2;
      float w0 = sW[slot][j + 0], w1 = sW[slot][j + 1];
      float w2 = sW[slot][j + 2], w3 = sW[slot][j + 3];
      float f0 = __half2float(*(const __half*)(hb + o0));
      float f1 = __half2float(*(const __half*)(hb + o1));
      float f2 = __half2float(*(const __half*)(hb + o2));
      float f3 = __half2float(*(const __half*)(hb + o3));
      acc = fmaf(w0, f0, acc); acc = fmaf(w1, f1, acc);
      acc = fmaf(w2, f2, acc); acc = fmaf(w3, f3, acc);
    }
    for (; j < degS; ++j) {
      unsigned o = (unsigned)sOff[slot][j] + cb2;
      float w = sW[slot][j];
      acc = fmaf(w, __half2float(*(const __half*)(hb + o)), acc);
    }
    if (deg > KCAP) {
      for (int e = rs + KCAP; e < re; ++e) {
        int s = csr_src[e];
        float u = expw(lrelu02(alS[s] + ad));
        den += u;
        acc = fmaf(u, __half2float(*(const __half*)(hb + ((unsigned)(s << RSH) + cb2))), acc);
      }
    }
    if (active) {
      ((float*)out)[(size_t)v * 32 + c] = acc / (den + 1e-16f) + bias[c];
    }
  }
}

// ---------------------------------------------------------------------------
extern "C" void kernel_launch(void* const* d_in, const int* in_sizes, int n_in,
                              void* d_out, int out_size, void* d_ws, size_t ws_size,
                              hipStream_t stream) {
  const float* x = (const float*)d_in[0];
  const void* ei = d_in[1];
  const float* w1 = (const float*)d_in[2];
  const float* as1 = (const float*)d_in[3];
  const float* ad1 = (const float*)d_in[4];
  const float* b1 = (const float*)d_in[5];
  const float* bn1w = (const float*)d_in[6];
  const float* bn1b = (const float*)d_in[7];
  const float* bn1m = (const float*)d_in[8];
  const float* bn1v = (const float*)d_in[9];
  const float* w2 = (const float*)d_in[10];
  const float* as2 = (const float*)d_in[11];
  const float* ad2 = (const float*)d_in[12];
  const float* b2 = (const float*)d_in[13];
  const float* bn2w = (const float*)d_in[14];
  const float* bn2b = (const float*)d_in[15];
  const float* bn2m = (const float*)d_in[16];
  const float* bn2v = (const float*)d_in[17];
  const float* w3 = (const float*)d_in[18];
  const float* as3 = (const float*)d_in[19];
  const float* ad3 = (const float*)d_in[20];
  const float* b3 = (const float*)d_in[21];

  const int N = in_sizes[0] / 128;
  const int E = in_sizes[1] / 2;
  const int nbk = (N + 127) / 128;
  const int chunk = (E + NBCHUNK - 1) / NBCHUNK;

  // workspace layout (256B aligned slices)
  char* base = (char*)d_ws;
  size_t off = 0;
  auto alloc = [&](size_t bytes) {
    void* p = base + off;
    off = (off + bytes + 255) & ~(size_t)255;
    return p;
  };
  int* flag = (int*)alloc(4);
  int* counts = (int*)alloc((size_t)NBCHUNK * nbk * 4);
  int* T = (int*)alloc((size_t)nbk * 4);
  int* EB = (int*)alloc((size_t)(nbk + 1) * 4);
  unsigned* binned = (unsigned*)alloc((size_t)E * 4);
  int* row_ptr = (int*)alloc((size_t)(N + 1) * 4);
  int* csr_src = (int*)alloc((size_t)(E + N) * 4);
  _Float16* Wt16 = (_Float16*)alloc((size_t)128 * 128 * 2);
  __half* hbuf = (__half*)alloc((size_t)N * 128 * 2);
  __half* gbuf = (__half*)alloc((size_t)N * 128 * 2);
  float* alS = (float*)alloc((size_t)N * 4 * 4);
  float* alD = (float*)alloc((size_t)N * 4 * 4);
  (void)ws_size;

  // ---- CSR build (no global atomics) ----
  detect_kernel<<<1, 64, 0, stream>>>((const unsigned*)ei, flag);
  bcount_kernel<<<NBCHUNK, 256, 0, stream>>>(ei, E, flag, counts, nbk, chunk);
  bscanT_kernel<<<nbk, NBCHUNK, 0, stream>>>(counts, T, nbk);
  bscanE_kernel<<<1, 64, 0, stream>>>(T, EB, nbk);
  bemit_kernel<<<NBCHUNK, 256, 0, stream>>>(ei, E, flag, counts, EB, nbk, chunk, binned);
  bscatter2_kernel<<<nbk, 256, 0, stream>>>(binned, EB, row_ptr, csr_src, N, E);

  const int rowBlocks = (N + 63) / 64;

  // ---- layer 1 ----
  wcvt_kernel<<<(128 * 128 + 255) / 256, 256, 0, stream>>>(w1, Wt16, 128);
  mfma_gemm_al_kernel<128, 4, float><<<rowBlocks, 256, 0, stream>>>(
      x, Wt16, as1, ad1, hbuf, alS, alD, N);
  agg_kernel<4, true, __half><<<(N + 3) / 4, 256, 0, stream>>>(
      row_ptr, csr_src, alS, alD, hbuf, b1, bn1w, bn1b, bn1m, bn1v, gbuf, N);
  // ---- layer 2 ----
  wcvt_kernel<<<(128 * 128 + 255) / 256, 256, 0, stream>>>(w2, Wt16, 128);
  mfma_gemm_al_kernel<128, 4, __half><<<rowBlocks, 256, 0, stream>>>(
      gbuf, Wt16, as2, ad2, hbuf, alS, alD, N);
  agg_kernel<4, true, __half><<<(N + 3) / 4, 256, 0, stream>>>(
      row_ptr, csr_src, alS, alD, hbuf, b2, bn2w, bn2b, bn2m, bn2v, gbuf, N);
  // ---- layer 3 ----
  wcvt_kernel<<<(128 * 32 + 255) / 256, 256, 0, stream>>>(w3, Wt16, 32);
  mfma_gemm_al_kernel<32, 1, __half><<<rowBlocks, 256, 0, stream>>>(
      gbuf, Wt16, as3, ad3, hbuf, alS, alD, N);
  agg_kernel<1, false, float><<<(N + 7) / 8, 256, 0, stream>>>(
      row_ptr, csr_src, alS, alD, hbuf, b3, nullptr, nullptr, nullptr, nullptr,
      (float*)d_out, N);
}

// Round 11
// 192.011 us; speedup vs baseline: 2.7724x; 1.0376x over previous
//
#include <hip/hip_runtime.h>
#include <hip/hip_fp16.h>
#include <cstdint>

// ---------------------------------------------------------------------------
// EpilepsyGNN: 3-layer GAT (4 heads x 32 -> 4x32 -> 1x32), BN(eval)+ReLU
// CSR build: bucketed two-phase scatter, zero global atomics.
// GEMM: MFMA f16 (v_mfma_f32_16x16x32_f16), LDS-staged A + W^T, f32 accum,
// al logits from f32 accumulators in the epilogue.
// agg: no-max softmax (scale-invariant, clamp-guarded), exp hoisted to
// staging; inner loop = edge-PAIR f16 gathers (half the wave handles edge j,
// half edge j+1; shfl_xor combine) -> half the gather instructions.
// ---------------------------------------------------------------------------

#define NBCHUNK 128   // edge chunks for bucket counting/emission
#define MAXBK 512     // max buckets of 128 nodes (N <= 65536; packing needs it)

typedef _Float16 f16x8 __attribute__((ext_vector_type(8)));
typedef float f32x4 __attribute__((ext_vector_type(4)));

__device__ __forceinline__ float lrelu02(float x) {
  return x > 0.f ? x : 0.2f * x;
}

__device__ __forceinline__ float expw(float x) {
  return __expf(fminf(x, 80.f));   // clamp is a no-op for this data; inf guard
}

// thread-0 sniff: int64 (little-endian) edge_index has all-odd words == 0
__device__ __forceinline__ int detect64(const unsigned* ei) {
  int is64 = 1;
  for (int i = 1; i < 128; i += 2)
    if (ei[i] != 0u) { is64 = 0; break; }
  return is64;
}

// --- phase 1: per-chunk LDS histogram of dst buckets ------------------------
__global__ __launch_bounds__(256) void bcount_kernel(const void* __restrict__ ei, int E,
                                                     int* __restrict__ counts,
                                                     int nbk, int chunk) {
  __shared__ int hist[MAXBK];
  __shared__ int sIs64;
  for (int i = threadIdx.x; i < nbk; i += 256) hist[i] = 0;
  if (threadIdx.x == 0) sIs64 = detect64((const unsigned*)ei);
  __syncthreads();
  int lo = blockIdx.x * chunk;
  int hi = lo + chunk; if (hi > E) hi = E;
  const bool is64 = sIs64 != 0;
  for (int e = lo + threadIdx.x; e < hi; e += 256) {
    int d = is64 ? (int)((const long long*)ei)[(size_t)E + e] : ((const int*)ei)[E + e];
    atomicAdd(&hist[d >> 7], 1);
  }
  __syncthreads();
  for (int i = threadIdx.x; i < nbk; i += 256)
    counts[(size_t)blockIdx.x * nbk + i] = hist[i];
}

// --- phase 2a: per-bucket exclusive scan over chunks; totals -> T -----------
__global__ void bscanT_kernel(int* __restrict__ counts, int* __restrict__ T, int nbk) {
  int b = blockIdx.x;
  int t = threadIdx.x;           // NBCHUNK = 128 threads
  int lane = t & 63;
  int v = counts[(size_t)t * nbk + b];
  int inc = v;
#pragma unroll
  for (int off = 1; off < 64; off <<= 1) {
    int u = __shfl_up(inc, off);
    if (lane >= off) inc += u;
  }
  __shared__ int w0;
  if (t == 63) w0 = inc;
  __syncthreads();
  int wb = (t >= 64) ? w0 : 0;
  counts[(size_t)t * nbk + b] = wb + inc - v;   // chunk-exclusive, bucket-local
  if (t == 127) T[b] = wb + inc;                // bucket edge total
}

// --- phase 2b: single-wave exclusive scan of bucket totals -> EB ------------
__global__ void bscanE_kernel(const int* __restrict__ T, int* __restrict__ EB, int nbk) {
  int lane = threadIdx.x;  // 64 threads
  int carry = 0;
  for (int start = 0; start < nbk; start += 64) {
    int i = start + lane;
    int v = (i < nbk) ? T[i] : 0;
    int inc = v;
#pragma unroll
    for (int off = 1; off < 64; off <<= 1) {
      int u = __shfl_up(inc, off);
      if (lane >= off) inc += u;
    }
    if (i < nbk) EB[i] = inc - v + carry;
    carry += __shfl(inc, 63);
  }
  if (lane == 0) EB[nbk] = carry;
}

// --- phase 3: emit packed (dloc<<16 | src) bucket-contiguously --------------
__global__ __launch_bounds__(256) void bemit_kernel(const void* __restrict__ ei, int E,
                                                    const int* __restrict__ counts,
                                                    const int* __restrict__ EB,
                                                    int nbk, int chunk,
                                                    unsigned* __restrict__ binned) {
  __shared__ int cur[MAXBK];
  __shared__ int sIs64;
  for (int i = threadIdx.x; i < nbk; i += 256)
    cur[i] = counts[(size_t)blockIdx.x * nbk + i] + EB[i];
  if (threadIdx.x == 0) sIs64 = detect64((const unsigned*)ei);
  __syncthreads();
  int lo = blockIdx.x * chunk;
  int hi = lo + chunk; if (hi > E) hi = E;
  const bool is64 = sIs64 != 0;
  for (int e = lo + threadIdx.x; e < hi; e += 256) {
    int s, d;
    if (is64) {
      const long long* p = (const long long*)ei;
      s = (int)p[e];
      d = (int)p[(size_t)E + e];
    } else {
      const int* p = (const int*)ei;
      s = p[e];
      d = p[E + e];
    }
    int pos = atomicAdd(&cur[d >> 7], 1);   // LDS atomic: cheap
    binned[pos] = ((unsigned)(d & 127) << 16) | (unsigned)s;   // N <= 65536
  }
}

// --- phase 4: per-bucket histogram -> row_ptr + self-loops + scatter --------
__global__ __launch_bounds__(256) void bscatter2_kernel(const unsigned* __restrict__ binned,
                                                        const int* __restrict__ EB,
                                                        int* __restrict__ row_ptr,
                                                        int* __restrict__ csr_src,
                                                        int n, int E) {
  __shared__ int hist[128];
  __shared__ int cur[128];
  __shared__ int w0s;
  const int b = blockIdx.x;
  const int t = threadIdx.x;
  const int bb = b << 7;
  if (t < 128) hist[t] = 0;
  __syncthreads();
  const int lo = EB[b], hi = EB[b + 1];
  for (int i = lo + t; i < hi; i += 256)
    atomicAdd(&hist[binned[i] >> 16], 1);
  __syncthreads();
  int lane = t & 63;
  int v = (t < 128) ? hist[t] : 0;
  int inc = v;
#pragma unroll
  for (int off = 1; off < 64; off <<= 1) {
    int u = __shfl_up(inc, off);
    if (lane >= off) inc += u;
  }
  if (t == 63) w0s = inc;
  __syncthreads();
  int exc = ((t >= 64 && t < 128) ? w0s : 0) + inc - v;
  if (t < 128 && bb + t < n) {
    int rp = EB[b] + bb + t + exc;   // edges-before-node + self-loops-before
    row_ptr[bb + t] = rp;
    csr_src[rp] = bb + t;            // self loop at slot 0
    cur[t] = rp + 1;
  }
  if (b == 0 && t == 0) row_ptr[n] = E + n;
  __syncthreads();
  for (int i = lo + t; i < hi; i += 256) {
    unsigned pv = binned[i];
    int pos = atomicAdd(&cur[pv >> 16], 1);
    csr_src[pos] = (int)(pv & 0xFFFFu);
  }
}

// --- all three W -> Wt f16 transposes in one launch -------------------------
__global__ void wcvt_all_kernel(const float* __restrict__ W1, const float* __restrict__ W2,
                                const float* __restrict__ W3,
                                _Float16* __restrict__ Wt1, _Float16* __restrict__ Wt2,
                                _Float16* __restrict__ Wt3) {
  int idx = blockIdx.x * 256 + threadIdx.x;
  if (idx < 16384) {
    int k = idx >> 7, c = idx & 127;
    Wt1[(size_t)c * 128 + k] = (_Float16)W1[idx];
  } else if (idx < 32768) {
    int i = idx - 16384;
    int k = i >> 7, c = i & 127;
    Wt2[(size_t)c * 128 + k] = (_Float16)W2[i];
  } else if (idx < 36864) {
    int i = idx - 32768;
    int k = i >> 5, c = i & 31;
    Wt3[(size_t)c * 128 + k] = (_Float16)W3[i];
  }
}

// --- MFMA GEMM + al epilogue: A[n,128]@W[128,OUTC] -> H(f16), alS/alD(f32) --
template <int OUTC, int H, typename AT>
__global__ __launch_bounds__(256) void mfma_gemm_al_kernel(
    const AT* __restrict__ A, const _Float16* __restrict__ Wt,
    const float* __restrict__ a_src, const float* __restrict__ a_dst,
    __half* __restrict__ Hout, float* __restrict__ alS, float* __restrict__ alD,
    int n) {
  constexpr int NT = OUTC / 16;    // col tiles per wave (8 or 2)
  constexpr int APH = 136;         // LDS row stride in halves (16B-aligned rows)

  __shared__ __align__(16) _Float16 A_lds[64 * APH];
  __shared__ __align__(16) _Float16 W_lds[OUTC * APH];

  const int t = threadIdx.x;
  const int r0 = blockIdx.x * 64;

  if constexpr (sizeof(AT) == 4) {
#pragma unroll
    for (int i = 0; i < 8; ++i) {
      int slot = t + i * 256;
      int r = slot >> 5, q = slot & 31;
      float4 v = make_float4(0.f, 0.f, 0.f, 0.f);
      if (r0 + r < n) v = *(const float4*)((const float*)A + (size_t)(r0 + r) * 128 + q * 4);
      __half2 p0 = __floats2half2_rn(v.x, v.y);
      __half2 p1 = __floats2half2_rn(v.z, v.w);
      uint2 pk;
      pk.x = *(unsigned*)&p0;
      pk.y = *(unsigned*)&p1;
      *(uint2*)&A_lds[r * APH + q * 4] = pk;
    }
  } else {
#pragma unroll
    for (int i = 0; i < 4; ++i) {
      int slot = t + i * 256;
      int r = slot >> 4, q = slot & 15;
      uint4 raw = make_uint4(0u, 0u, 0u, 0u);
      if (r0 + r < n) raw = *(const uint4*)((const __half*)A + (size_t)(r0 + r) * 128 + q * 8);
      *(uint4*)&A_lds[r * APH + q * 8] = raw;
    }
  }
#pragma unroll
  for (int i = 0; i < OUTC / 16; ++i) {
    int slot = t + i * 256;
    int c = slot >> 4, q = slot & 15;
    uint4 raw = *(const uint4*)(Wt + (size_t)c * 128 + q * 8);
    *(uint4*)&W_lds[c * APH + q * 8] = raw;
  }
  __syncthreads();

  const int w = t >> 6;
  const int lane = t & 63;
  const int lrow = lane & 15;
  const int lk = lane >> 4;

  f32x4 acc[NT];
#pragma unroll
  for (int i = 0; i < NT; ++i) acc[i] = (f32x4){0.f, 0.f, 0.f, 0.f};

#pragma unroll
  for (int kc = 0; kc < 4; ++kc) {
    f16x8 a = *(const f16x8*)&A_lds[(w * 16 + lrow) * APH + kc * 32 + lk * 8];
#pragma unroll
    for (int ct = 0; ct < NT; ++ct) {
      f16x8 b = *(const f16x8*)&W_lds[(ct * 16 + lrow) * APH + kc * 32 + lk * 8];
      acc[ct] = __builtin_amdgcn_mfma_f32_16x16x32_f16(a, b, acc[ct], 0, 0, 0);
    }
  }

  const int rbase = r0 + w * 16 + lk * 4;
#pragma unroll
  for (int ct = 0; ct < NT; ++ct) {
#pragma unroll
    for (int j = 0; j < 4; ++j) {
      int r = rbase + j;
      if (r < n) Hout[(size_t)r * OUTC + ct * 16 + lrow] = __float2half(acc[ct][j]);
    }
  }

#pragma unroll
  for (int h = 0; h < H; ++h) {
    float as0 = a_src[h * 32 + lrow], as1 = a_src[h * 32 + 16 + lrow];
    float ad0 = a_dst[h * 32 + lrow], ad1 = a_dst[h * 32 + 16 + lrow];
#pragma unroll
    for (int j = 0; j < 4; ++j) {
      float ps = acc[2 * h][j] * as0 + acc[2 * h + 1][j] * as1;
      float pd = acc[2 * h][j] * ad0 + acc[2 * h + 1][j] * ad1;
#pragma unroll
      for (int off = 1; off < 16; off <<= 1) {
        ps += __shfl_xor(ps, off);
        pd += __shfl_xor(pd, off);
      }
      if (lrow == 0) {
        int r = rbase + j;
        if (r < n) {
          alS[(size_t)r * H + h] = ps;
          alD[(size_t)r * H + h] = pd;
        }
      }
    }
  }
}

// --- agg: staged exp weights, edge-PAIR f16 gathers, shfl combine -----------
template <int H, bool BN, typename OutT>
__global__ __launch_bounds__(256) void agg_kernel(
    const int* __restrict__ row_ptr, const int* __restrict__ csr_src,
    const float* __restrict__ alS, const float* __restrict__ alD,
    const __half* __restrict__ hfeat, const float* __restrict__ bias,
    const float* __restrict__ bnw, const float* __restrict__ bnb,
    const float* __restrict__ bnm, const float* __restrict__ bnv,
    OutT* __restrict__ out, int n) {
  constexpr int LPN = (H == 4) ? 64 : 32;     // lanes per node
  constexpr int NPB = 256 / LPN;              // node slots per block
  constexpr int KCAP = 96;                    // staged-edge capacity
  constexpr int RSH = (H == 4) ? 8 : 6;       // log2(row bytes): 256B / 64B

  __shared__ __align__(16) float sW[NPB][KCAP * H];
  __shared__ int sOff[NPB][KCAP];

  const int slot = threadIdx.x / LPN;
  const int sl = threadIdx.x % LPN;
  const int v = blockIdx.x * NPB + slot;
  const bool active = v < n;
  const char* hb = (const char*)hfeat;

  int rs = 0, re = 0;
  if (active) { rs = row_ptr[v]; re = row_ptr[v + 1]; }
  const int deg = re - rs;
  const int degS = deg < KCAP ? deg : KCAP;

  if constexpr (H == 4) {
    float4 ad4 = make_float4(0.f, 0.f, 0.f, 0.f);
    if (active) ad4 = *(const float4*)(alD + (size_t)v * 4);
    float den0 = 0.f, den1 = 0.f, den2 = 0.f, den3 = 0.f;
    for (int k = sl; k < degS; k += 64) {
      int s = csr_src[rs + k];
      sOff[slot][k] = s << RSH;
      float4 a4 = *(const float4*)(alS + (size_t)s * 4);
      float u0 = expw(lrelu02(a4.x + ad4.x));
      float u1 = expw(lrelu02(a4.y + ad4.y));
      float u2 = expw(lrelu02(a4.z + ad4.z));
      float u3 = expw(lrelu02(a4.w + ad4.w));
      ((float4*)&sW[slot][0])[k] = make_float4(u0, u1, u2, u3);
      den0 += u0; den1 += u1; den2 += u2; den3 += u3;
    }
#pragma unroll
    for (int off = 32; off >= 1; off >>= 1) {
      den0 += __shfl_xor(den0, off);
      den1 += __shfl_xor(den1, off);
      den2 += __shfl_xor(den2, off);
      den3 += __shfl_xor(den3, off);
    }

    // edge-pair: lanes 0-31 even edges, lanes 32-63 odd edges; 4 ch/lane
    const int half = sl >> 5;
    const int l5 = sl & 31;
    const int c = l5 * 4;
    const int h = l5 >> 3;
    const unsigned cb2 = (unsigned)(c * 2);
    float a0 = 0.f, a1 = 0.f, a2 = 0.f, a3 = 0.f;
    int j = 0;
    for (; j + 8 <= degS; j += 8) {
      int e0 = j + half, e1 = j + 2 + half, e2 = j + 4 + half, e3 = j + 6 + half;
      unsigned o0 = (unsigned)sOff[slot][e0] + cb2;
      unsigned o1 = (unsigned)sOff[slot][e1] + cb2;
      unsigned o2 = (unsigned)sOff[slot][e2] + cb2;
      unsigned o3 = (unsigned)sOff[slot][e3] + cb2;
      float w0 = sW[slot][e0 * 4 + h], w1 = sW[slot][e1 * 4 + h];
      float w2 = sW[slot][e2 * 4 + h], w3 = sW[slot][e3 * 4 + h];
      uint2 r0v = *(const uint2*)(hb + o0);
      uint2 r1v = *(const uint2*)(hb + o1);
      uint2 r2v = *(const uint2*)(hb + o2);
      uint2 r3v = *(const uint2*)(hb + o3);
      float2 f0l = __half22float2(*(const __half2*)&r0v.x);
      float2 f0h = __half22float2(*(const __half2*)&r0v.y);
      float2 f1l = __half22float2(*(const __half2*)&r1v.x);
      float2 f1h = __half22float2(*(const __half2*)&r1v.y);
      float2 f2l = __half22float2(*(const __half2*)&r2v.x);
      float2 f2h = __half22float2(*(const __half2*)&r2v.y);
      float2 f3l = __half22float2(*(const __half2*)&r3v.x);
      float2 f3h = __half22float2(*(const __half2*)&r3v.y);
      a0 = fmaf(w0, f0l.x, a0); a1 = fmaf(w0, f0l.y, a1);
      a2 = fmaf(w0, f0h.x, a2); a3 = fmaf(w0, f0h.y, a3);
      a0 = fmaf(w1, f1l.x, a0); a1 = fmaf(w1, f1l.y, a1);
      a2 = fmaf(w1, f1h.x, a2); a3 = fmaf(w1, f1h.y, a3);
      a0 = fmaf(w2, f2l.x, a0); a1 = fmaf(w2, f2l.y, a1);
      a2 = fmaf(w2, f2h.x, a2); a3 = fmaf(w2, f2h.y, a3);
      a0 = fmaf(w3, f3l.x, a0); a1 = fmaf(w3, f3l.y, a1);
      a2 = fmaf(w3, f3h.x, a2); a3 = fmaf(w3, f3h.y, a3);
    }
    for (; j + 2 <= degS; j += 2) {
      int e = j + half;
      unsigned o = (unsigned)sOff[slot][e] + cb2;
      float w = sW[slot][e * 4 + h];
      uint2 rv = *(const uint2*)(hb + o);
      float2 fl = __half22float2(*(const __half2*)&rv.x);
      float2 fh = __half22float2(*(const __half2*)&rv.y);
      a0 = fmaf(w, fl.x, a0); a1 = fmaf(w, fl.y, a1);
      a2 = fmaf(w, fh.x, a2); a3 = fmaf(w, fh.y, a3);
    }
    if ((degS & 1) && half == 0) {
      int e = degS - 1;
      unsigned o = (unsigned)sOff[slot][e] + cb2;
      float w = sW[slot][e * 4 + h];
      uint2 rv = *(const uint2*)(hb + o);
      float2 fl = __half22float2(*(const __half2*)&rv.x);
      float2 fh = __half22float2(*(const __half2*)&rv.y);
      a0 = fmaf(w, fl.x, a0); a1 = fmaf(w, fl.y, a1);
      a2 = fmaf(w, fh.x, a2); a3 = fmaf(w, fh.y, a3);
    }
    a0 += __shfl_xor(a0, 32);
    a1 += __shfl_xor(a1, 32);
    a2 += __shfl_xor(a2, 32);
    a3 += __shfl_xor(a3, 32);

    float den = (h == 0) ? den0 : (h == 1) ? den1 : (h == 2) ? den2 : den3;
    if (deg > KCAP) {  // cold fallback (serial, never triggers at deg~17)
      float adh = alD[(size_t)v * 4 + h];
      if (half == 0) {
        for (int e = rs + KCAP; e < re; ++e) {
          int s = csr_src[e];
          float u = expw(lrelu02(alS[(size_t)s * 4 + h] + adh));
          den += u;
          uint2 rv = *(const uint2*)(hb + ((unsigned)(s << RSH) + cb2));
          float2 fl = __half22float2(*(const __half2*)&rv.x);
          float2 fh = __half22float2(*(const __half2*)&rv.y);
          a0 = fmaf(u, fl.x, a0); a1 = fmaf(u, fl.y, a1);
          a2 = fmaf(u, fh.x, a2); a3 = fmaf(u, fh.y, a3);
        }
      } else {
        for (int e = rs + KCAP; e < re; ++e) {
          int s = csr_src[e];
          den += expw(lrelu02(alS[(size_t)s * 4 + h] + adh));
        }
      }
    }
    if (active && half == 0) {
      float inv = 1.f / (den + 1e-16f);
      float4 b4 = *(const float4*)(bias + c);
      float g0 = a0 * inv + b4.x;
      float g1 = a1 * inv + b4.y;
      float g2 = a2 * inv + b4.z;
      float g3 = a3 * inv + b4.w;
      if constexpr (BN) {
        float4 bw = *(const float4*)(bnw + c);
        float4 bb = *(const float4*)(bnb + c);
        float4 bm = *(const float4*)(bnm + c);
        float4 bv = *(const float4*)(bnv + c);
        g0 = fmaxf((g0 - bm.x) * (bw.x * rsqrtf(bv.x + 1e-5f)) + bb.x, 0.f);
        g1 = fmaxf((g1 - bm.y) * (bw.y * rsqrtf(bv.y + 1e-5f)) + bb.y, 0.f);
        g2 = fmaxf((g2 - bm.z) * (bw.z * rsqrtf(bv.z + 1e-5f)) + bb.z, 0.f);
        g3 = fmaxf((g3 - bm.w) * (bw.w * rsqrtf(bv.w + 1e-5f)) + bb.w, 0.f);
      }
      if constexpr (sizeof(OutT) == 2) {
        __half2 p0 = __floats2half2_rn(g0, g1);
        __half2 p1 = __floats2half2_rn(g2, g3);
        uint2 pk;
        pk.x = *(unsigned*)&p0;
        pk.y = *(unsigned*)&p1;
        *(uint2*)((__half*)out + (size_t)v * 128 + c) = pk;
      } else {
        *(float4*)((float*)out + (size_t)v * 128 + c) = make_float4(g0, g1, g2, g3);
      }
    }
  } else {  // H == 1, C == 32
    float ad = active ? alD[v] : 0.f;
    float den = 0.f;
    for (int k = sl; k < degS; k += 32) {
      int s = csr_src[rs + k];
      sOff[slot][k] = s << RSH;
      float u = expw(lrelu02(alS[s] + ad));
      sW[slot][k] = u;
      den += u;
    }
#pragma unroll
    for (int off = 16; off >= 1; off >>= 1) den += __shfl_xor(den, off);

    // edge-pair: lanes 0-15 even edges, 16-31 odd; 2 ch/lane (__half2)
    const int quad = sl >> 4;
    const int l4 = sl & 15;
    const int c2 = l4 * 2;
    const unsigned cb2 = (unsigned)(c2 * 2);
    float a0 = 0.f, a1 = 0.f;
    int j = 0;
    for (; j + 4 <= degS; j += 4) {
      int e0 = j + quad, e1 = j + 2 + quad;
      unsigned o0 = (unsigned)sOff[slot][e0] + cb2;
      unsigned o1 = (unsigned)sOff[slot][e1] + cb2;
      float w0 = sW[slot][e0], w1 = sW[slot][e1];
      float2 f0 = __half22float2(*(const __half2*)(hb + o0));
      float2 f1 = __half22float2(*(const __half2*)(hb + o1));
      a0 = fmaf(w0, f0.x, a0); a1 = fmaf(w0, f0.y, a1);
      a0 = fmaf(w1, f1.x, a0); a1 = fmaf(w1, f1.y, a1);
    }
    for (; j + 2 <= degS; j += 2) {
      int e = j + quad;
      unsigned o = (unsigned)sOff[slot][e] + cb2;
      float w = sW[slot][e];
      float2 f = __half22float2(*(const __half2*)(hb + o));
      a0 = fmaf(w, f.x, a0); a1 = fmaf(w, f.y, a1);
    }
    if ((degS & 1) && quad == 0) {
      int e = degS - 1;
      unsigned o = (unsigned)sOff[slot][e] + cb2;
      float w = sW[slot][e];
      float2 f = __half22float2(*(const __half2*)(hb + o));
      a0 = fmaf(w, f.x, a0); a1 = fmaf(w, f.y, a1);
    }
    a0 += __shfl_xor(a0, 16);
    a1 += __shfl_xor(a1, 16);

    if (deg > KCAP) {
      if (quad == 0) {
        for (int e = rs + KCAP; e < re; ++e) {
          int s = csr_src[e];
          float u = expw(lrelu02(alS[s] + ad));
          den += u;
          float2 f = __half22float2(*(const __half2*)(hb + ((unsigned)(s << RSH) + cb2)));
          a0 = fmaf(u, f.x, a0); a1 = fmaf(u, f.y, a1);
        }
      } else {
        for (int e = rs + KCAP; e < re; ++e)
          den += expw(lrelu02(alS[csr_src[e]] + ad));
      }
    }
    if (active && quad == 0) {
      float inv = 1.f / (den + 1e-16f);
      float2 b2v = *(const float2*)(bias + c2);
      ((float2*)((float*)out + (size_t)v * 32))[l4] =
          make_float2(a0 * inv + b2v.x, a1 * inv + b2v.y);
    }
  }
}

// ---------------------------------------------------------------------------
extern "C" void kernel_launch(void* const* d_in, const int* in_sizes, int n_in,
                              void* d_out, int out_size, void* d_ws, size_t ws_size,
                              hipStream_t stream) {
  const float* x = (const float*)d_in[0];
  const void* ei = d_in[1];
  const float* w1 = (const float*)d_in[2];
  const float* as1 = (const float*)d_in[3];
  const float* ad1 = (const float*)d_in[4];
  const float* b1 = (const float*)d_in[5];
  const float* bn1w = (const float*)d_in[6];
  const float* bn1b = (const float*)d_in[7];
  const float* bn1m = (const float*)d_in[8];
  const float* bn1v = (const float*)d_in[9];
  const float* w2 = (const float*)d_in[10];
  const float* as2 = (const float*)d_in[11];
  const float* ad2 = (const float*)d_in[12];
  const float* b2 = (const float*)d_in[13];
  const float* bn2w = (const float*)d_in[14];
  const float* bn2b = (const float*)d_in[15];
  const float* bn2m = (const float*)d_in[16];
  const float* bn2v = (const float*)d_in[17];
  const float* w3 = (const float*)d_in[18];
  const float* as3 = (const float*)d_in[19];
  const float* ad3 = (const float*)d_in[20];
  const float* b3 = (const float*)d_in[21];

  const int N = in_sizes[0] / 128;
  const int E = in_sizes[1] / 2;
  const int nbk = (N + 127) / 128;
  const int chunk = (E + NBCHUNK - 1) / NBCHUNK;

  // workspace layout (256B aligned slices)
  char* base = (char*)d_ws;
  size_t off = 0;
  auto alloc = [&](size_t bytes) {
    void* p = base + off;
    off = (off + bytes + 255) & ~(size_t)255;
    return p;
  };
  int* counts = (int*)alloc((size_t)NBCHUNK * nbk * 4);
  int* T = (int*)alloc((size_t)nbk * 4);
  int* EB = (int*)alloc((size_t)(nbk + 1) * 4);
  unsigned* binned = (unsigned*)alloc((size_t)E * 4);
  int* row_ptr = (int*)alloc((size_t)(N + 1) * 4);
  int* csr_src = (int*)alloc((size_t)(E + N) * 4);
  _Float16* Wt1 = (_Float16*)alloc((size_t)128 * 128 * 2);
  _Float16* Wt2 = (_Float16*)alloc((size_t)128 * 128 * 2);
  _Float16* Wt3 = (_Float16*)alloc((size_t)32 * 128 * 2);
  __half* hbuf = (__half*)alloc((size_t)N * 128 * 2);
  __half* gbuf = (__half*)alloc((size_t)N * 128 * 2);
  float* alS = (float*)alloc((size_t)N * 4 * 4);
  float* alD = (float*)alloc((size_t)N * 4 * 4);
  (void)ws_size;

  // ---- weights + CSR build (no global atomics) ----
  wcvt_all_kernel<<<144, 256, 0, stream>>>(w1, w2, w3, Wt1, Wt2, Wt3);
  bcount_kernel<<<NBCHUNK, 256, 0, stream>>>(ei, E, counts, nbk, chunk);
  bscanT_kernel<<<nbk, NBCHUNK, 0, stream>>>(counts, T, nbk);
  bscanE_kernel<<<1, 64, 0, stream>>>(T, EB, nbk);
  bemit_kernel<<<NBCHUNK, 256, 0, stream>>>(ei, E, counts, EB, nbk, chunk, binned);
  bscatter2_kernel<<<nbk, 256, 0, stream>>>(binned, EB, row_ptr, csr_src, N, E);

  const int rowBlocks = (N + 63) / 64;

  // ---- layer 1 ----
  mfma_gemm_al_kernel<128, 4, float><<<rowBlocks, 256, 0, stream>>>(
      x, Wt1, as1, ad1, hbuf, alS, alD, N);
  agg_kernel<4, true, __half><<<(N + 3) / 4, 256, 0, stream>>>(
      row_ptr, csr_src, alS, alD, hbuf, b1, bn1w, bn1b, bn1m, bn1v, gbuf, N);
  // ---- layer 2 ----
  mfma_gemm_al_kernel<128, 4, __half><<<rowBlocks, 256, 0, stream>>>(
      gbuf, Wt2, as2, ad2, hbuf, alS, alD, N);
  agg_kernel<4, true, __half><<<(N + 3) / 4, 256, 0, stream>>>(
      row_ptr, csr_src, alS, alD, hbuf, b2, bn2w, bn2b, bn2m, bn2v, gbuf, N);
  // ---- layer 3 ----
  mfma_gemm_al_kernel<32, 1, __half><<<rowBlocks, 256, 0, stream>>>(
      gbuf, Wt3, as3, ad3, hbuf, alS, alD, N);
  agg_kernel<1, false, float><<<(N + 7) / 8, 256, 0, stream>>>(
      row_ptr, csr_src, alS, alD, hbuf, b3, nullptr, nullptr, nullptr, nullptr,
      (float*)d_out, N);
}